// Round 6
// baseline (1640.862 us; speedup 1.0000x reference)
//
#include <hip/hip_runtime.h>
#include <hip/hip_bf16.h>

#define NN 50000
#define NE 800000
#define NG 500
#define NF 128
#define NH 64
#define SCAN_B ((NN + 255)/256)   // 196

typedef unsigned int u32;
typedef unsigned short u16;

__device__ __forceinline__ float bflo(u32 p){ return __uint_as_float(p << 16); }
__device__ __forceinline__ float bfhi(u32 p){ return __uint_as_float(p & 0xffff0000u); }
__device__ __forceinline__ float bf1(u16 v){ return __uint_as_float(((u32)v) << 16); }

__device__ __forceinline__ void cv8(uint4 q, float* dst){
  dst[0]=bflo(q.x); dst[1]=bfhi(q.x);
  dst[2]=bflo(q.y); dst[3]=bfhi(q.y);
  dst[4]=bflo(q.z); dst[5]=bfhi(q.z);
  dst[6]=bflo(q.w); dst[7]=bfhi(q.w);
}

// ---- dtype probe (f32 inputs -> flag=0; proven by R1-NaN/R5-counters, kept as hedge)
__global__ void k_detect(const u32* __restrict__ x, int* __restrict__ flag){
  int lane = threadIdx.x;
  u32 w = x[lane];
  u32 lo = w & 0xFFFFu;
  u32 e = (lo >> 7) & 0xFFu;
  bool vote = (e >= 0x60u && e <= 0x8Fu);
  unsigned long long m = __ballot(vote);
  if (lane == 0) flag[0] = (__popcll(m) >= 32) ? 1 : 0;
}

// ---- graph boundaries
__global__ void k_bounds(const int* __restrict__ batch, int* __restrict__ starts){
  int g = threadIdx.x;
  if (g > NG) return;
  int lo = 0, hi = NN;
  while (lo < hi){ int mid = (lo + hi) >> 1; if (batch[mid] < g) lo = mid + 1; else hi = mid; }
  starts[g] = lo;
}

// ---- CSR build: degree count
__global__ __launch_bounds__(256) void k_count(const int* __restrict__ ei, int* __restrict__ deg){
  int e = blockIdx.x*256 + threadIdx.x;
  if (e >= NE) return;
  atomicAdd(&deg[ei[NE + e]], 1);
}

// ---- hierarchical coalesced scan (3 phases)
__global__ __launch_bounds__(256) void k_scanA(const int* __restrict__ deg, int* __restrict__ bsum){
  __shared__ int red[256];
  int t = threadIdx.x;
  int i = blockIdx.x*256 + t;
  red[t] = (i < NN) ? deg[i] : 0;
  __syncthreads();
  for (int off = 128; off > 0; off >>= 1){
    if (t < off) red[t] += red[t+off];
    __syncthreads();
  }
  if (t == 0) bsum[blockIdx.x] = red[0];
}

__global__ __launch_bounds__(256) void k_scanB(int* __restrict__ bsum){
  __shared__ int part[256];
  int t = threadIdx.x;
  int v = (t < SCAN_B) ? bsum[t] : 0;
  part[t] = v;
  __syncthreads();
  for (int off = 1; off < 256; off <<= 1){
    int u = (t >= off) ? part[t-off] : 0;
    __syncthreads();
    part[t] += u;
    __syncthreads();
  }
  if (t < SCAN_B) bsum[t] = part[t] - v;   // exclusive
}

__global__ __launch_bounds__(256) void k_scanC(const int* __restrict__ deg, const int* __restrict__ bsum,
    int* __restrict__ rowptr, int* __restrict__ cursor){
  __shared__ int part[256];
  int t = threadIdx.x;
  int i = blockIdx.x*256 + t;
  int v = (i < NN) ? deg[i] : 0;
  part[t] = v;
  __syncthreads();
  for (int off = 1; off < 256; off <<= 1){
    int u = (t >= off) ? part[t-off] : 0;
    __syncthreads();
    part[t] += u;
    __syncthreads();
  }
  int ex = part[t] - v + bsum[blockIdx.x];
  if (i < NN){ rowptr[i] = ex; cursor[i] = ex; }
  if (blockIdx.x == 0 && t == 0) rowptr[NN] = NE;
}

// ---- CSR fill
__global__ __launch_bounds__(256) void k_fill(const int* __restrict__ ei,
    int* __restrict__ cursor, int* __restrict__ csr){
  int e = blockIdx.x*256 + threadIdx.x;
  if (e >= NE) return;
  int dst = ei[NE + e];
  int slot = atomicAdd(&cursor[dst], 1);
  csr[slot] = ei[e];
}

// ---- gather: U[node] = h[node] + sum_{src} h[src]; block 0 also re-zeros s1/s2
__global__ __launch_bounds__(256) void k_gather(const float* __restrict__ h,
    const int* __restrict__ rowptr, const int* __restrict__ csr, float* __restrict__ U,
    float* __restrict__ s1){
  if (blockIdx.x == 0 && threadIdx.x < 128) s1[threadIdx.x] = 0.f;  // s1[0:64]=s1, s1[64:128]=s2
  int wid = threadIdx.x >> 6, lane = threadIdx.x & 63;
  int node = blockIdx.x*4 + wid;
  if (node >= NN) return;
  int chunk = lane & 15, epar = lane >> 4;
  int beg = rowptr[node], en = rowptr[node+1];
  float4 acc;
  if (epar == 0) acc = *(const float4*)&h[(size_t)node*NH + chunk*4];
  else { acc.x=0.f; acc.y=0.f; acc.z=0.f; acc.w=0.f; }
  for (int j = beg + epar; j < en; j += 4){
    int src = csr[j];
    float4 v = *(const float4*)&h[(size_t)src*NH + chunk*4];
    acc.x += v.x; acc.y += v.y; acc.z += v.z; acc.w += v.w;
  }
  acc.x += __shfl_xor(acc.x, 16); acc.y += __shfl_xor(acc.y, 16);
  acc.z += __shfl_xor(acc.z, 16); acc.w += __shfl_xor(acc.w, 16);
  acc.x += __shfl_xor(acc.x, 32); acc.y += __shfl_xor(acc.y, 32);
  acc.z += __shfl_xor(acc.z, 32); acc.w += __shfl_xor(acc.w, 32);
  if (epar == 0) *(float4*)&U[(size_t)node*NH + chunk*4] = acc;
}

// ---- transform (bf16 path, hedge): unchanged from R4
__global__ __launch_bounds__(256) void k_transform_b(const u16* __restrict__ x,
    const u16* __restrict__ Wt, const u16* __restrict__ bt, const int* __restrict__ flag,
    float* __restrict__ t, float* __restrict__ s1, float* __restrict__ s2){
  if (flag[0] == 0) return;
  __shared__ float sW[NF*NH];
  __shared__ u16 sX[64*136];
  int tid = threadIdx.x;
  for (int i = tid*8; i < NF*NH; i += 2048){
    cv8(*(const uint4*)(Wt + i), &sW[i]);
  }
  int node0 = blockIdx.x*64;
  int nrows = min(64, NN - node0);
  for (int i = tid; i < 1024; i += 256){
    int r = i >> 4, c8 = i & 15;
    uint4 q;
    if (r < nrows) q = *(const uint4*)(x + (size_t)(node0+r)*NF + c8*8);
    else { q.x=0; q.y=0; q.z=0; q.w=0; }
    *(uint4*)&sX[r*136 + c8*8] = q;
  }
  __syncthreads();
  int lane = tid & 63, w = tid >> 6, c0 = w*16;
  float acc[16];
  #pragma unroll
  for (int cc = 0; cc < 16; cc++) acc[cc] = bf1(bt[c0+cc]);
  for (int k2 = 0; k2 < 64; k2++){
    u32 p = *(const u32*)&sX[lane*136 + k2*2];
    float u0 = bflo(p), u1 = bfhi(p);
    const float4* w0 = (const float4*)&sW[(2*k2)*NH + c0];
    const float4* w1 = (const float4*)&sW[(2*k2+1)*NH + c0];
    float4 a0=w0[0], a1=w0[1], a2=w0[2], a3=w0[3];
    float4 b0=w1[0], b1=w1[1], b2=w1[2], b3=w1[3];
    acc[0]+=u0*a0.x+u1*b0.x; acc[1]+=u0*a0.y+u1*b0.y; acc[2]+=u0*a0.z+u1*b0.z; acc[3]+=u0*a0.w+u1*b0.w;
    acc[4]+=u0*a1.x+u1*b1.x; acc[5]+=u0*a1.y+u1*b1.y; acc[6]+=u0*a1.z+u1*b1.z; acc[7]+=u0*a1.w+u1*b1.w;
    acc[8]+=u0*a2.x+u1*b2.x; acc[9]+=u0*a2.y+u1*b2.y; acc[10]+=u0*a2.z+u1*b2.z; acc[11]+=u0*a2.w+u1*b2.w;
    acc[12]+=u0*a3.x+u1*b3.x; acc[13]+=u0*a3.y+u1*b3.y; acc[14]+=u0*a3.z+u1*b3.z; acc[15]+=u0*a3.w+u1*b3.w;
  }
  bool ok = (lane < nrows);
  if (ok){
    float* dst = &t[(size_t)(node0+lane)*NH + c0];
    #pragma unroll
    for (int q4 = 0; q4 < 4; q4++){
      float4 v; v.x=acc[q4*4]; v.y=acc[q4*4+1]; v.z=acc[q4*4+2]; v.w=acc[q4*4+3];
      *(float4*)&dst[q4*4] = v;
    }
  }
  #pragma unroll
  for (int cc = 0; cc < 16; cc++){
    float v = ok ? acc[cc] : 0.f;
    float v2 = v*v;
    #pragma unroll
    for (int m = 1; m < 64; m <<= 1){ v += __shfl_xor(v, m); v2 += __shfl_xor(v2, m); }
    if (lane == 0){
      unsafeAtomicAdd(&s1[c0+cc], v);
      unsafeAtomicAdd(&s2[c0+cc], v2);
    }
  }
}

// ---- transform (f32 FAST path): lane=row, wave=16 cols, weights broadcast from LDS
__global__ __launch_bounds__(256) void k_transform_f(const float* __restrict__ x,
    const float* __restrict__ Wt, const float* __restrict__ bt, const int* __restrict__ flag,
    float* __restrict__ t, float* __restrict__ s1, float* __restrict__ s2){
  if (flag[0] != 0) return;
  __shared__ float sW[NF*NH];     // 32 KB [k][c]
  int tid = threadIdx.x;
  for (int i = tid*4; i < NF*NH; i += 1024)
    *(float4*)&sW[i] = *(const float4*)(Wt + i);
  __syncthreads();
  int node0 = blockIdx.x*64;
  int nrows = min(64, NN - node0);
  int lane = tid & 63, w = tid >> 6, c0 = w*16;
  int row = node0 + lane;
  bool ok = (row < NN);
  int rc = ok ? row : (NN-1);                      // clamp: valid memory, masked later
  const float4* xr = (const float4*)(x + (size_t)rc*NF);
  float acc[16];
  #pragma unroll
  for (int cc = 0; cc < 16; cc++) acc[cc] = bt[c0+cc];
  #pragma unroll 4
  for (int k4 = 0; k4 < 32; k4++){
    float4 u = xr[k4];
    #pragma unroll
    for (int j = 0; j < 4; j++){
      float uj = (j==0)?u.x:((j==1)?u.y:((j==2)?u.z:u.w));
      const float4* wr = (const float4*)&sW[(k4*4+j)*NH + c0];
      float4 a0=wr[0], a1=wr[1], a2=wr[2], a3=wr[3];
      acc[0]+=uj*a0.x; acc[1]+=uj*a0.y; acc[2]+=uj*a0.z; acc[3]+=uj*a0.w;
      acc[4]+=uj*a1.x; acc[5]+=uj*a1.y; acc[6]+=uj*a1.z; acc[7]+=uj*a1.w;
      acc[8]+=uj*a2.x; acc[9]+=uj*a2.y; acc[10]+=uj*a2.z; acc[11]+=uj*a2.w;
      acc[12]+=uj*a3.x; acc[13]+=uj*a3.y; acc[14]+=uj*a3.z; acc[15]+=uj*a3.w;
    }
  }
  if (ok){
    float* dst = &t[(size_t)row*NH + c0];
    #pragma unroll
    for (int q4 = 0; q4 < 4; q4++){
      float4 v; v.x=acc[q4*4]; v.y=acc[q4*4+1]; v.z=acc[q4*4+2]; v.w=acc[q4*4+3];
      *(float4*)&dst[q4*4] = v;
    }
  }
  #pragma unroll
  for (int cc = 0; cc < 16; cc++){
    float v = ok ? acc[cc] : 0.f;
    float v2 = v*v;
    #pragma unroll
    for (int m = 1; m < 64; m <<= 1){ v += __shfl_xor(v, m); v2 += __shfl_xor(v2, m); }
    if (lane == 0){
      unsafeAtomicAdd(&s1[c0+cc], v);
      unsafeAtomicAdd(&s2[c0+cc], v2);
    }
  }
}

// ---- per-graph embed with FUSED BN-fold (replaces k_bnfinal)
__global__ __launch_bounds__(256) void k_embed(const float* __restrict__ t,
    const float* __restrict__ s1, const float* __restrict__ s2,
    const void* __restrict__ gamma, const void* __restrict__ beta, int ofs,
    float* __restrict__ h, const int* __restrict__ starts, const int* __restrict__ flag,
    void* __restrict__ dout, int layer){
  __shared__ float sRed[8*NH];
  int g = blockIdx.x;
  int tx = threadIdx.x & 63, ty = threadIdx.x >> 6;
  int bf = flag[0];
  float gm = bf ? bf1(((const u16*)gamma)[ofs+tx]) : ((const float*)gamma)[ofs+tx];
  float be = bf ? bf1(((const u16*)beta)[ofs+tx])  : ((const float*)beta)[ofs+tx];
  float mean = s1[tx] * (1.f/NN);
  float var  = s2[tx] * (1.f/NN) - mean*mean;
  float rr = rsqrtf(fmaxf(var, 0.f) + 1e-5f);
  float sc = gm * rr;
  float sh = be - mean*sc;
  int st = starts[g], en = starts[g+1];
  float ls1 = 0.f, ls2 = 0.f;
  for (int n = st + ty; n < en; n += 4){
    float z = t[(size_t)n*NH + tx] * sc + sh;
    h[(size_t)n*NH + tx] = z;
    ls1 += z; ls2 += z*z;
  }
  sRed[ty*NH + tx] = ls1;
  sRed[(4+ty)*NH + tx] = ls2;
  __syncthreads();
  if (ty == 0){
    float a1 = sRed[tx] + sRed[NH+tx] + sRed[2*NH+tx] + sRed[3*NH+tx];
    float a2 = sRed[4*NH+tx] + sRed[5*NH+tx] + sRed[6*NH+tx] + sRed[7*NH+tx];
    int cnt = en - st;
    float inv = 1.f / (float)max(cnt, 1);
    float m = a1 * inv;
    float vv = a2 * inv - m*m;
    float s = sqrtf(fmaxf(vv, 0.f));
    size_t eidx = ((size_t)layer*NG + g)*NH + tx;
    size_t sidx = (size_t)4*NG*NH + eidx;
    if (bf){
      ((__hip_bfloat16*)dout)[eidx] = __float2bfloat16(m);
      ((__hip_bfloat16*)dout)[sidx] = __float2bfloat16(s);
    } else {
      ((float*)dout)[eidx] = m;
      ((float*)dout)[sidx] = s;
    }
  }
}

// ---- MLP (bf16 path, hedge): unchanged from R4
__global__ __launch_bounds__(256) void k_mlp_b(float* __restrict__ U,
    const u16* __restrict__ W1, const u16* __restrict__ W2, int wofs,
    const int* __restrict__ flag, float* __restrict__ s1, float* __restrict__ s2){
  if (flag[0] == 0) return;
  __shared__ float sW1[NH*NH];
  __shared__ float sW2[NH*NH];
  __shared__ float sU[64*65];
  int tid = threadIdx.x;
  for (int i = tid*8; i < NH*NH; i += 2048){
    cv8(*(const uint4*)(W1 + wofs + i), &sW1[i]);
    cv8(*(const uint4*)(W2 + wofs + i), &sW2[i]);
  }
  int node0 = blockIdx.x*64;
  int nrows = min(64, NN - node0);
  for (int i = tid; i < 1024; i += 256){
    int r = i >> 4, c4 = i & 15;
    float4 q;
    if (r < nrows) q = *(const float4*)&U[(size_t)(node0+r)*NH + c4*4];
    else { q.x=0.f; q.y=0.f; q.z=0.f; q.w=0.f; }
    float* d = &sU[r*65 + c4*4];
    d[0]=q.x; d[1]=q.y; d[2]=q.z; d[3]=q.w;
  }
  __syncthreads();
  int lane = tid & 63, w = tid >> 6, c0 = w*16;
  float va[16];
  #pragma unroll
  for (int cc = 0; cc < 16; cc++) va[cc] = 0.f;
  for (int k = 0; k < 64; k++){
    float u = sU[lane*65 + k];
    const float4* wr = (const float4*)&sW1[k*NH + c0];
    float4 a0=wr[0], a1=wr[1], a2=wr[2], a3=wr[3];
    va[0]+=u*a0.x; va[1]+=u*a0.y; va[2]+=u*a0.z; va[3]+=u*a0.w;
    va[4]+=u*a1.x; va[5]+=u*a1.y; va[6]+=u*a1.z; va[7]+=u*a1.w;
    va[8]+=u*a2.x; va[9]+=u*a2.y; va[10]+=u*a2.z; va[11]+=u*a2.w;
    va[12]+=u*a3.x; va[13]+=u*a3.y; va[14]+=u*a3.z; va[15]+=u*a3.w;
  }
  __syncthreads();
  #pragma unroll
  for (int cc = 0; cc < 16; cc++) sU[lane*65 + c0 + cc] = fmaxf(va[cc], 0.f);
  __syncthreads();
  #pragma unroll
  for (int cc = 0; cc < 16; cc++) va[cc] = 0.f;
  for (int k = 0; k < 64; k++){
    float u = sU[lane*65 + k];
    const float4* wr = (const float4*)&sW2[k*NH + c0];
    float4 a0=wr[0], a1=wr[1], a2=wr[2], a3=wr[3];
    va[0]+=u*a0.x; va[1]+=u*a0.y; va[2]+=u*a0.z; va[3]+=u*a0.w;
    va[4]+=u*a1.x; va[5]+=u*a1.y; va[6]+=u*a1.z; va[7]+=u*a1.w;
    va[8]+=u*a2.x; va[9]+=u*a2.y; va[10]+=u*a2.z; va[11]+=u*a2.w;
    va[12]+=u*a3.x; va[13]+=u*a3.y; va[14]+=u*a3.z; va[15]+=u*a3.w;
  }
  #pragma unroll
  for (int cc = 0; cc < 16; cc++) va[cc] = fmaxf(va[cc], 0.f);
  bool ok = (lane < nrows);
  if (ok){
    float* dst = &U[(size_t)(node0+lane)*NH + c0];
    #pragma unroll
    for (int q4 = 0; q4 < 4; q4++){
      float4 v; v.x=va[q4*4]; v.y=va[q4*4+1]; v.z=va[q4*4+2]; v.w=va[q4*4+3];
      *(float4*)&dst[q4*4] = v;
    }
  }
  #pragma unroll
  for (int cc = 0; cc < 16; cc++){
    float v = va[cc];
    float v2 = v*v;
    #pragma unroll
    for (int m = 1; m < 64; m <<= 1){ v += __shfl_xor(v, m); v2 += __shfl_xor(v2, m); }
    if (lane == 0){
      unsafeAtomicAdd(&s1[c0+cc], v);
      unsafeAtomicAdd(&s2[c0+cc], v2);
    }
  }
}

// ---- MLP (f32 FAST path): same structure as k_mlp_b, float4 weight loads
__global__ __launch_bounds__(256) void k_mlp_f(float* __restrict__ U,
    const float* __restrict__ W1, const float* __restrict__ W2, int wofs,
    const int* __restrict__ flag, float* __restrict__ s1, float* __restrict__ s2){
  if (flag[0] != 0) return;
  __shared__ float sW1[NH*NH];
  __shared__ float sW2[NH*NH];
  __shared__ float sU[64*65];
  int tid = threadIdx.x;
  for (int i = tid*4; i < NH*NH; i += 1024){
    *(float4*)&sW1[i] = *(const float4*)(W1 + wofs + i);
    *(float4*)&sW2[i] = *(const float4*)(W2 + wofs + i);
  }
  int node0 = blockIdx.x*64;
  int nrows = min(64, NN - node0);
  for (int i = tid; i < 1024; i += 256){
    int r = i >> 4, c4 = i & 15;
    float4 q;
    if (r < nrows) q = *(const float4*)&U[(size_t)(node0+r)*NH + c4*4];
    else { q.x=0.f; q.y=0.f; q.z=0.f; q.w=0.f; }
    float* d = &sU[r*65 + c4*4];
    d[0]=q.x; d[1]=q.y; d[2]=q.z; d[3]=q.w;
  }
  __syncthreads();
  int lane = tid & 63, w = tid >> 6, c0 = w*16;
  float va[16];
  #pragma unroll
  for (int cc = 0; cc < 16; cc++) va[cc] = 0.f;
  for (int k = 0; k < 64; k++){
    float u = sU[lane*65 + k];
    const float4* wr = (const float4*)&sW1[k*NH + c0];
    float4 a0=wr[0], a1=wr[1], a2=wr[2], a3=wr[3];
    va[0]+=u*a0.x; va[1]+=u*a0.y; va[2]+=u*a0.z; va[3]+=u*a0.w;
    va[4]+=u*a1.x; va[5]+=u*a1.y; va[6]+=u*a1.z; va[7]+=u*a1.w;
    va[8]+=u*a2.x; va[9]+=u*a2.y; va[10]+=u*a2.z; va[11]+=u*a2.w;
    va[12]+=u*a3.x; va[13]+=u*a3.y; va[14]+=u*a3.z; va[15]+=u*a3.w;
  }
  __syncthreads();
  #pragma unroll
  for (int cc = 0; cc < 16; cc++) sU[lane*65 + c0 + cc] = fmaxf(va[cc], 0.f);
  __syncthreads();
  #pragma unroll
  for (int cc = 0; cc < 16; cc++) va[cc] = 0.f;
  for (int k = 0; k < 64; k++){
    float u = sU[lane*65 + k];
    const float4* wr = (const float4*)&sW2[k*NH + c0];
    float4 a0=wr[0], a1=wr[1], a2=wr[2], a3=wr[3];
    va[0]+=u*a0.x; va[1]+=u*a0.y; va[2]+=u*a0.z; va[3]+=u*a0.w;
    va[4]+=u*a1.x; va[5]+=u*a1.y; va[6]+=u*a1.z; va[7]+=u*a1.w;
    va[8]+=u*a2.x; va[9]+=u*a2.y; va[10]+=u*a2.z; va[11]+=u*a2.w;
    va[12]+=u*a3.x; va[13]+=u*a3.y; va[14]+=u*a3.z; va[15]+=u*a3.w;
  }
  #pragma unroll
  for (int cc = 0; cc < 16; cc++) va[cc] = fmaxf(va[cc], 0.f);
  bool ok = (lane < nrows);
  if (ok){
    float* dst = &U[(size_t)(node0+lane)*NH + c0];
    #pragma unroll
    for (int q4 = 0; q4 < 4; q4++){
      float4 v; v.x=va[q4*4]; v.y=va[q4*4+1]; v.z=va[q4*4+2]; v.w=va[q4*4+3];
      *(float4*)&dst[q4*4] = v;
    }
  }
  #pragma unroll
  for (int cc = 0; cc < 16; cc++){
    float v = va[cc];
    float v2 = v*v;
    #pragma unroll
    for (int m = 1; m < 64; m <<= 1){ v += __shfl_xor(v, m); v2 += __shfl_xor(v2, m); }
    if (lane == 0){
      unsafeAtomicAdd(&s1[c0+cc], v);
      unsafeAtomicAdd(&s2[c0+cc], v2);
    }
  }
}

extern "C" void kernel_launch(void* const* d_in, const int* in_sizes, int n_in,
                              void* d_out, int out_size, void* d_ws, size_t ws_size,
                              hipStream_t stream) {
  const void* x    = d_in[0];
  const int* ei    = (const int*)d_in[1];
  const int* batch = (const int*)d_in[2];
  const void* Wt   = d_in[3];
  const void* bt   = d_in[4];
  const void* g0   = d_in[5];
  const void* b0   = d_in[6];
  const void* W1   = d_in[7];
  const void* W2   = d_in[8];
  const void* gs   = d_in[9];
  const void* bs   = d_in[10];

  float* hbuf = (float*)d_ws;           // NN*NH f32
  float* ubuf = hbuf + (size_t)NN*NH;   // NN*NH f32 (U, then in-place T)
  float* s1   = ubuf + (size_t)NN*NH;   // 64
  float* s2   = s1 + NH;                // 64  (contiguous after s1)
  float* scA  = s2 + NH;                // 64 (unused, layout kept)
  float* shB  = scA + NH;               // 64
  int* starts = (int*)(shB + NH);       // 512
  int* flag   = starts + 512;           // 64 (padded)
  int* deg    = flag + 64;              // NN
  int* rowptr = deg + NN;               // NN+64
  int* cursor = rowptr + NN + 64;       // NN
  int* csr    = cursor + NN;            // NE
  int* bsum   = csr + NE;               // 256

  hipMemsetAsync(s1, 0, 2*NH*sizeof(float), stream);
  hipMemsetAsync(deg, 0, NN*sizeof(int), stream);
  k_detect<<<1, 64, 0, stream>>>((const u32*)x, flag);
  k_bounds<<<1, 512, 0, stream>>>(batch, starts);
  k_count<<<(NE+255)/256, 256, 0, stream>>>(ei, deg);
  k_scanA<<<SCAN_B, 256, 0, stream>>>(deg, bsum);
  k_scanB<<<1, 256, 0, stream>>>(bsum);
  k_scanC<<<SCAN_B, 256, 0, stream>>>(deg, bsum, rowptr, cursor);
  k_fill<<<(NE+255)/256, 256, 0, stream>>>(ei, cursor, csr);

  k_transform_b<<<(NN+63)/64, 256, 0, stream>>>((const u16*)x, (const u16*)Wt, (const u16*)bt, flag, ubuf, s1, s2);
  k_transform_f<<<(NN+63)/64, 256, 0, stream>>>((const float*)x, (const float*)Wt, (const float*)bt, flag, ubuf, s1, s2);
  k_embed<<<NG, 256, 0, stream>>>(ubuf, s1, s2, g0, b0, 0, hbuf, starts, flag, d_out, 0);

  for (int l = 0; l < 3; l++){
    k_gather<<<(NN+3)/4, 256, 0, stream>>>(hbuf, rowptr, csr, ubuf, s1);  // also zeros s1/s2
    k_mlp_b<<<(NN+63)/64, 256, 0, stream>>>(ubuf, (const u16*)W1, (const u16*)W2, l*NH*NH, flag, s1, s2);
    k_mlp_f<<<(NN+63)/64, 256, 0, stream>>>(ubuf, (const float*)W1, (const float*)W2, l*NH*NH, flag, s1, s2);
    k_embed<<<NG, 256, 0, stream>>>(ubuf, s1, s2, gs, bs, l*NH, hbuf, starts, flag, d_out, l+1);
  }
}

// Round 7
// 596.602 us; speedup vs baseline: 2.7503x; 2.7503x over previous
//
#include <hip/hip_runtime.h>
#include <hip/hip_bf16.h>

#define NN 50000
#define NE 800000
#define NG 500
#define NF 128
#define NH 64
#define SCAN_B ((NN + 255)/256)   // 196

typedef unsigned int u32;
typedef unsigned short u16;

__device__ __forceinline__ float bf1(u16 v){ return __uint_as_float(((u32)v) << 16); }

// ---- dtype probe (f32 inputs proven; kept as output-format hedge)
__global__ void k_detect(const u32* __restrict__ x, int* __restrict__ flag){
  int lane = threadIdx.x;
  u32 w = x[lane];
  u32 lo = w & 0xFFFFu;
  u32 e = (lo >> 7) & 0xFFu;
  bool vote = (e >= 0x60u && e <= 0x8Fu);
  unsigned long long m = __ballot(vote);
  if (lane == 0) flag[0] = (__popcll(m) >= 32) ? 1 : 0;
}

// ---- graph boundaries
__global__ void k_bounds(const int* __restrict__ batch, int* __restrict__ starts){
  int g = threadIdx.x;
  if (g > NG) return;
  int lo = 0, hi = NN;
  while (lo < hi){ int mid = (lo + hi) >> 1; if (batch[mid] < g) lo = mid + 1; else hi = mid; }
  starts[g] = lo;
}

// ---- CSR build: degree count
__global__ __launch_bounds__(256) void k_count(const int* __restrict__ ei, int* __restrict__ deg){
  int e = blockIdx.x*256 + threadIdx.x;
  if (e >= NE) return;
  atomicAdd(&deg[ei[NE + e]], 1);
}

// ---- hierarchical coalesced scan (3 phases)
__global__ __launch_bounds__(256) void k_scanA(const int* __restrict__ deg, int* __restrict__ bsum){
  __shared__ int red[256];
  int t = threadIdx.x;
  int i = blockIdx.x*256 + t;
  red[t] = (i < NN) ? deg[i] : 0;
  __syncthreads();
  for (int off = 128; off > 0; off >>= 1){
    if (t < off) red[t] += red[t+off];
    __syncthreads();
  }
  if (t == 0) bsum[blockIdx.x] = red[0];
}

__global__ __launch_bounds__(256) void k_scanB(int* __restrict__ bsum){
  __shared__ int part[256];
  int t = threadIdx.x;
  int v = (t < SCAN_B) ? bsum[t] : 0;
  part[t] = v;
  __syncthreads();
  for (int off = 1; off < 256; off <<= 1){
    int u = (t >= off) ? part[t-off] : 0;
    __syncthreads();
    part[t] += u;
    __syncthreads();
  }
  if (t < SCAN_B) bsum[t] = part[t] - v;   // exclusive
}

__global__ __launch_bounds__(256) void k_scanC(const int* __restrict__ deg, const int* __restrict__ bsum,
    int* __restrict__ rowptr, int* __restrict__ cursor){
  __shared__ int part[256];
  int t = threadIdx.x;
  int i = blockIdx.x*256 + t;
  int v = (i < NN) ? deg[i] : 0;
  part[t] = v;
  __syncthreads();
  for (int off = 1; off < 256; off <<= 1){
    int u = (t >= off) ? part[t-off] : 0;
    __syncthreads();
    part[t] += u;
    __syncthreads();
  }
  int ex = part[t] - v + bsum[blockIdx.x];
  if (i < NN){ rowptr[i] = ex; cursor[i] = ex; }
  if (blockIdx.x == 0 && t == 0) rowptr[NN] = NE;
}

// ---- CSR fill
__global__ __launch_bounds__(256) void k_fill(const int* __restrict__ ei,
    int* __restrict__ cursor, int* __restrict__ csr){
  int e = blockIdx.x*256 + threadIdx.x;
  if (e >= NE) return;
  int dst = ei[NE + e];
  int slot = atomicAdd(&cursor[dst], 1);
  csr[slot] = ei[e];
}

// ---- gather: U[node] = h[node] + sum_{src} h[src]; block 0 re-zeros s1/s2
__global__ __launch_bounds__(256) void k_gather(const float* __restrict__ h,
    const int* __restrict__ rowptr, const int* __restrict__ csr, float* __restrict__ U,
    float* __restrict__ s1){
  if (blockIdx.x == 0 && threadIdx.x < 128) s1[threadIdx.x] = 0.f;  // s1[0:64], s2[64:128]
  int wid = threadIdx.x >> 6, lane = threadIdx.x & 63;
  int node = blockIdx.x*4 + wid;
  if (node >= NN) return;
  int chunk = lane & 15, epar = lane >> 4;
  int beg = rowptr[node], en = rowptr[node+1];
  float4 acc;
  if (epar == 0) acc = *(const float4*)&h[(size_t)node*NH + chunk*4];
  else { acc.x=0.f; acc.y=0.f; acc.z=0.f; acc.w=0.f; }
  for (int j = beg + epar; j < en; j += 4){
    int src = csr[j];
    float4 v = *(const float4*)&h[(size_t)src*NH + chunk*4];
    acc.x += v.x; acc.y += v.y; acc.z += v.z; acc.w += v.w;
  }
  acc.x += __shfl_xor(acc.x, 16); acc.y += __shfl_xor(acc.y, 16);
  acc.z += __shfl_xor(acc.z, 16); acc.w += __shfl_xor(acc.w, 16);
  acc.x += __shfl_xor(acc.x, 32); acc.y += __shfl_xor(acc.y, 32);
  acc.z += __shfl_xor(acc.z, 32); acc.w += __shfl_xor(acc.w, 32);
  if (epar == 0) *(float4*)&U[(size_t)node*NH + chunk*4] = acc;
}

// ---- transform (R5-proven structure + row-pairing): t = x@Wt + bt; stats
__global__ __launch_bounds__(256) void k_transform_f(const float* __restrict__ x,
    const float* __restrict__ Wt, const float* __restrict__ bt,
    float* __restrict__ t, float* __restrict__ s1, float* __restrict__ s2){
  __shared__ float sW[NF*NH];     // 32 KB [k][c]
  __shared__ float sRed[8*NH];
  int tid = threadIdx.x;
  for (int i = tid*4; i < NF*NH; i += 1024)
    *(float4*)&sW[i] = *(const float4*)(Wt + i);
  __syncthreads();
  int tx = tid & 63, ty = tid >> 6;
  int row0 = blockIdx.x*64 + ty*16;
  float b = bt[tx];
  float ls1 = 0.f, ls2 = 0.f;
  for (int i = 0; i < 8; i++){
    int ra = row0 + i, rb = row0 + i + 8;
    bool oa = (ra < NN), ob = (rb < NN);
    const float4* xa = (const float4*)(x + (size_t)(oa ? ra : 0)*NF);
    const float4* xb = (const float4*)(x + (size_t)(ob ? rb : 0)*NF);
    float acca = b, accb = b;
    #pragma unroll
    for (int k4 = 0; k4 < 32; k4++){
      float4 fa = xa[k4];
      float4 fb = xb[k4];
      int kb = k4*4;
      float w0 = sW[(kb+0)*NH+tx];
      float w1 = sW[(kb+1)*NH+tx];
      float w2 = sW[(kb+2)*NH+tx];
      float w3 = sW[(kb+3)*NH+tx];
      acca += fa.x*w0 + fa.y*w1 + fa.z*w2 + fa.w*w3;
      accb += fb.x*w0 + fb.y*w1 + fb.z*w2 + fb.w*w3;
    }
    if (oa){ t[(size_t)ra*NH + tx] = acca; ls1 += acca; ls2 += acca*acca; }
    if (ob){ t[(size_t)rb*NH + tx] = accb; ls1 += accb; ls2 += accb*accb; }
  }
  sRed[ty*NH + tx] = ls1;
  sRed[(4+ty)*NH + tx] = ls2;
  __syncthreads();
  if (ty == 0){
    float a1 = sRed[tx] + sRed[NH+tx] + sRed[2*NH+tx] + sRed[3*NH+tx];
    float a2 = sRed[4*NH+tx] + sRed[5*NH+tx] + sRed[6*NH+tx] + sRed[7*NH+tx];
    unsafeAtomicAdd(&s1[tx], a1);
    unsafeAtomicAdd(&s2[tx], a2);
  }
}

// ---- per-graph embed with fused BN-fold
__global__ __launch_bounds__(256) void k_embed(const float* __restrict__ t,
    const float* __restrict__ s1, const float* __restrict__ s2,
    const void* __restrict__ gamma, const void* __restrict__ beta, int ofs,
    float* __restrict__ h, const int* __restrict__ starts, const int* __restrict__ flag,
    void* __restrict__ dout, int layer){
  __shared__ float sRed[8*NH];
  int g = blockIdx.x;
  int tx = threadIdx.x & 63, ty = threadIdx.x >> 6;
  int bf = flag[0];
  float gm = bf ? bf1(((const u16*)gamma)[ofs+tx]) : ((const float*)gamma)[ofs+tx];
  float be = bf ? bf1(((const u16*)beta)[ofs+tx])  : ((const float*)beta)[ofs+tx];
  float mean = s1[tx] * (1.f/NN);
  float var  = s2[tx] * (1.f/NN) - mean*mean;
  float rr = rsqrtf(fmaxf(var, 0.f) + 1e-5f);
  float sc = gm * rr;
  float sh = be - mean*sc;
  int st = starts[g], en = starts[g+1];
  float ls1 = 0.f, ls2 = 0.f;
  for (int n = st + ty; n < en; n += 4){
    float z = t[(size_t)n*NH + tx] * sc + sh;
    h[(size_t)n*NH + tx] = z;
    ls1 += z; ls2 += z*z;
  }
  sRed[ty*NH + tx] = ls1;
  sRed[(4+ty)*NH + tx] = ls2;
  __syncthreads();
  if (ty == 0){
    float a1 = sRed[tx] + sRed[NH+tx] + sRed[2*NH+tx] + sRed[3*NH+tx];
    float a2 = sRed[4*NH+tx] + sRed[5*NH+tx] + sRed[6*NH+tx] + sRed[7*NH+tx];
    int cnt = en - st;
    float inv = 1.f / (float)max(cnt, 1);
    float m = a1 * inv;
    float vv = a2 * inv - m*m;
    float s = sqrtf(fmaxf(vv, 0.f));
    size_t eidx = ((size_t)layer*NG + g)*NH + tx;
    size_t sidx = (size_t)4*NG*NH + eidx;
    if (bf){
      ((__hip_bfloat16*)dout)[eidx] = __float2bfloat16(m);
      ((__hip_bfloat16*)dout)[sidx] = __float2bfloat16(s);
    } else {
      ((float*)dout)[eidx] = m;
      ((float*)dout)[sidx] = s;
    }
  }
}

// ---- MLP (R5-proven broadcast structure + row-pairing): in-place relu(relu(U@W1)@W2)
__global__ __launch_bounds__(256) void k_mlp_f(float* __restrict__ U,
    const float* __restrict__ W1, const float* __restrict__ W2, int wofs,
    float* __restrict__ s1, float* __restrict__ s2){
  __shared__ float sU[64*NH];    // 16 KB
  __shared__ float sV[64*NH];    // 16 KB
  __shared__ float sW1[NH*NH];   // 16 KB (reused as reduction scratch)
  __shared__ float sW2[NH*NH];   // 16 KB
  int tid = threadIdx.x;
  for (int i = tid*4; i < NH*NH; i += 1024){
    *(float4*)&sW1[i] = *(const float4*)(W1 + wofs + i);
    *(float4*)&sW2[i] = *(const float4*)(W2 + wofs + i);
  }
  int node0 = blockIdx.x*64;
  int nrows = min(64, NN - node0);
  // stage full 64 rows, zero-pad the tail so unguarded reads are safe
  for (int i = tid; i < 1024; i += 256){
    int r = i >> 4, c4 = i & 15;
    float4 q;
    if (r < nrows) q = *(const float4*)&U[(size_t)(node0+r)*NH + c4*4];
    else { q.x=0.f; q.y=0.f; q.z=0.f; q.w=0.f; }
    *(float4*)&sU[r*NH + c4*4] = q;
  }
  __syncthreads();
  int tx = tid & 63, ty = tid >> 6;
  // phase A: V = relu(U @ W1), rows paired to share weight reads
  for (int i = 0; i < 8; i++){
    int ra = ty*16 + i, rb = ra + 8;
    const float4* ua = (const float4*)&sU[ra*NH];
    const float4* ub = (const float4*)&sU[rb*NH];
    float acca = 0.f, accb = 0.f;
    #pragma unroll
    for (int k4 = 0; k4 < 16; k4++){
      float4 a = ua[k4];
      float4 bq = ub[k4];
      float w0 = sW1[(k4*4+0)*NH+tx];
      float w1 = sW1[(k4*4+1)*NH+tx];
      float w2 = sW1[(k4*4+2)*NH+tx];
      float w3 = sW1[(k4*4+3)*NH+tx];
      acca += a.x*w0 + a.y*w1 + a.z*w2 + a.w*w3;
      accb += bq.x*w0 + bq.y*w1 + bq.z*w2 + bq.w*w3;
    }
    sV[ra*NH + tx] = fmaxf(acca, 0.f);
    sV[rb*NH + tx] = fmaxf(accb, 0.f);
  }
  __syncthreads();
  // phase B: T = relu(V @ W2), in-place to U
  float ls1 = 0.f, ls2 = 0.f;
  for (int i = 0; i < 8; i++){
    int ra = ty*16 + i, rb = ra + 8;
    const float4* va = (const float4*)&sV[ra*NH];
    const float4* vb = (const float4*)&sV[rb*NH];
    float acca = 0.f, accb = 0.f;
    #pragma unroll
    for (int k4 = 0; k4 < 16; k4++){
      float4 a = va[k4];
      float4 bq = vb[k4];
      float w0 = sW2[(k4*4+0)*NH+tx];
      float w1 = sW2[(k4*4+1)*NH+tx];
      float w2 = sW2[(k4*4+2)*NH+tx];
      float w3 = sW2[(k4*4+3)*NH+tx];
      acca += a.x*w0 + a.y*w1 + a.z*w2 + a.w*w3;
      accb += bq.x*w0 + bq.y*w1 + bq.z*w2 + bq.w*w3;
    }
    float ta = fmaxf(acca, 0.f), tb = fmaxf(accb, 0.f);
    if (ra < nrows){ U[(size_t)(node0+ra)*NH + tx] = ta; ls1 += ta; ls2 += ta*ta; }
    if (rb < nrows){ U[(size_t)(node0+rb)*NH + tx] = tb; ls1 += tb; ls2 += tb*tb; }
  }
  __syncthreads();
  sW1[ty*NH + tx] = ls1;
  sW1[(4+ty)*NH + tx] = ls2;
  __syncthreads();
  if (ty == 0){
    float a1 = sW1[tx] + sW1[NH+tx] + sW1[2*NH+tx] + sW1[3*NH+tx];
    float a2 = sW1[4*NH+tx] + sW1[5*NH+tx] + sW1[6*NH+tx] + sW1[7*NH+tx];
    unsafeAtomicAdd(&s1[tx], a1);
    unsafeAtomicAdd(&s2[tx], a2);
  }
}

extern "C" void kernel_launch(void* const* d_in, const int* in_sizes, int n_in,
                              void* d_out, int out_size, void* d_ws, size_t ws_size,
                              hipStream_t stream) {
  const void* x    = d_in[0];
  const int* ei    = (const int*)d_in[1];
  const int* batch = (const int*)d_in[2];
  const void* Wt   = d_in[3];
  const void* bt   = d_in[4];
  const void* g0   = d_in[5];
  const void* b0   = d_in[6];
  const void* W1   = d_in[7];
  const void* W2   = d_in[8];
  const void* gs   = d_in[9];
  const void* bs   = d_in[10];

  float* hbuf = (float*)d_ws;           // NN*NH f32
  float* ubuf = hbuf + (size_t)NN*NH;   // NN*NH f32 (U, then in-place T)
  float* s1   = ubuf + (size_t)NN*NH;   // 64
  float* s2   = s1 + NH;                // 64 (contiguous after s1)
  float* pad  = s2 + NH;                // 128 (layout spacer)
  int* starts = (int*)(pad + 2*NH);     // 512
  int* flag   = starts + 512;           // 64 (padded)
  int* deg    = flag + 64;              // NN
  int* rowptr = deg + NN;               // NN+64
  int* cursor = rowptr + NN + 64;       // NN
  int* csr    = cursor + NN;            // NE
  int* bsum   = csr + NE;               // 256

  hipMemsetAsync(s1, 0, 2*NH*sizeof(float), stream);
  hipMemsetAsync(deg, 0, NN*sizeof(int), stream);
  k_detect<<<1, 64, 0, stream>>>((const u32*)x, flag);
  k_bounds<<<1, 512, 0, stream>>>(batch, starts);
  k_count<<<(NE+255)/256, 256, 0, stream>>>(ei, deg);
  k_scanA<<<SCAN_B, 256, 0, stream>>>(deg, bsum);
  k_scanB<<<1, 256, 0, stream>>>(bsum);
  k_scanC<<<SCAN_B, 256, 0, stream>>>(deg, bsum, rowptr, cursor);
  k_fill<<<(NE+255)/256, 256, 0, stream>>>(ei, cursor, csr);

  k_transform_f<<<(NN+63)/64, 256, 0, stream>>>((const float*)x, (const float*)Wt, (const float*)bt, ubuf, s1, s2);
  k_embed<<<NG, 256, 0, stream>>>(ubuf, s1, s2, g0, b0, 0, hbuf, starts, flag, d_out, 0);

  for (int l = 0; l < 3; l++){
    k_gather<<<(NN+3)/4, 256, 0, stream>>>(hbuf, rowptr, csr, ubuf, s1);  // also zeros s1/s2
    k_mlp_f<<<(NN+63)/64, 256, 0, stream>>>(ubuf, (const float*)W1, (const float*)W2, l*NH*NH, s1, s2);
    k_embed<<<NG, 256, 0, stream>>>(ubuf, s1, s2, gs, bs, l*NH, hbuf, starts, flag, d_out, l+1);
  }
}

// Round 8
// 510.468 us; speedup vs baseline: 3.2144x; 1.1687x over previous
//
#include <hip/hip_runtime.h>
#include <hip/hip_bf16.h>

#define NN 50000
#define NE 800000
#define NG 500
#define NF 128
#define NH 64
#define SCAN_B ((NN + 255)/256)   // 196

typedef unsigned int u32;
typedef unsigned short u16;

__device__ __forceinline__ float bf1(u16 v){ return __uint_as_float(((u32)v) << 16); }
__device__ __forceinline__ float bflo(u32 p){ return __uint_as_float(p << 16); }
__device__ __forceinline__ float bfhi(u32 p){ return __uint_as_float(p & 0xffff0000u); }
__device__ __forceinline__ void cv8(uint4 q, float* dst){
  dst[0]=bflo(q.x); dst[1]=bfhi(q.x);
  dst[2]=bflo(q.y); dst[3]=bfhi(q.y);
  dst[4]=bflo(q.z); dst[5]=bfhi(q.z);
  dst[6]=bflo(q.w); dst[7]=bfhi(q.w);
}
__device__ __forceinline__ u16 f2b(float f){
  u32 u = __float_as_uint(f);
  u32 r = (u + 0x7fffu + ((u >> 16) & 1u)) >> 16;   // RNE
  return (u16)r;
}

// ---- dtype probe (f32 inputs proven; kept as output-format hedge)
__global__ void k_detect(const u32* __restrict__ x, int* __restrict__ flag){
  int lane = threadIdx.x;
  u32 w = x[lane];
  u32 lo = w & 0xFFFFu;
  u32 e = (lo >> 7) & 0xFFu;
  bool vote = (e >= 0x60u && e <= 0x8Fu);
  unsigned long long m = __ballot(vote);
  if (lane == 0) flag[0] = (__popcll(m) >= 32) ? 1 : 0;
}

// ---- graph boundaries
__global__ void k_bounds(const int* __restrict__ batch, int* __restrict__ starts){
  int g = threadIdx.x;
  if (g > NG) return;
  int lo = 0, hi = NN;
  while (lo < hi){ int mid = (lo + hi) >> 1; if (batch[mid] < g) lo = mid + 1; else hi = mid; }
  starts[g] = lo;
}

// ---- CSR build: degree count
__global__ __launch_bounds__(256) void k_count(const int* __restrict__ ei, int* __restrict__ deg){
  int e = blockIdx.x*256 + threadIdx.x;
  if (e >= NE) return;
  atomicAdd(&deg[ei[NE + e]], 1);
}

// ---- hierarchical coalesced scan (3 phases)
__global__ __launch_bounds__(256) void k_scanA(const int* __restrict__ deg, int* __restrict__ bsum){
  __shared__ int red[256];
  int t = threadIdx.x;
  int i = blockIdx.x*256 + t;
  red[t] = (i < NN) ? deg[i] : 0;
  __syncthreads();
  for (int off = 128; off > 0; off >>= 1){
    if (t < off) red[t] += red[t+off];
    __syncthreads();
  }
  if (t == 0) bsum[blockIdx.x] = red[0];
}

__global__ __launch_bounds__(256) void k_scanB(int* __restrict__ bsum){
  __shared__ int part[256];
  int t = threadIdx.x;
  int v = (t < SCAN_B) ? bsum[t] : 0;
  part[t] = v;
  __syncthreads();
  for (int off = 1; off < 256; off <<= 1){
    int u = (t >= off) ? part[t-off] : 0;
    __syncthreads();
    part[t] += u;
    __syncthreads();
  }
  if (t < SCAN_B) bsum[t] = part[t] - v;   // exclusive
}

__global__ __launch_bounds__(256) void k_scanC(const int* __restrict__ deg, const int* __restrict__ bsum,
    int* __restrict__ rowptr, int* __restrict__ cursor){
  __shared__ int part[256];
  int t = threadIdx.x;
  int i = blockIdx.x*256 + t;
  int v = (i < NN) ? deg[i] : 0;
  part[t] = v;
  __syncthreads();
  for (int off = 1; off < 256; off <<= 1){
    int u = (t >= off) ? part[t-off] : 0;
    __syncthreads();
    part[t] += u;
    __syncthreads();
  }
  int ex = part[t] - v + bsum[blockIdx.x];
  if (i < NN){ rowptr[i] = ex; cursor[i] = ex; }
  if (blockIdx.x == 0 && t == 0) rowptr[NN] = NE;
}

// ---- CSR fill
__global__ __launch_bounds__(256) void k_fill(const int* __restrict__ ei,
    int* __restrict__ cursor, int* __restrict__ csr){
  int e = blockIdx.x*256 + threadIdx.x;
  if (e >= NE) return;
  int dst = ei[NE + e];
  int slot = atomicAdd(&cursor[dst], 1);
  csr[slot] = ei[e];
}

// ---- gather (bf16 h): U[node] = h[node] + sum_{src} h[src]; block 0 re-zeros s1/s2
//      lane = 8 edge-slots x 8 column-chunks (8 bf16 = 16B per chunk)
__global__ __launch_bounds__(256) void k_gather(const u16* __restrict__ h,
    const int* __restrict__ rowptr, const int* __restrict__ csr, float* __restrict__ U,
    float* __restrict__ s1){
  if (blockIdx.x == 0 && threadIdx.x < 128) s1[threadIdx.x] = 0.f;  // s1[0:64], s2[64:128]
  int wid = threadIdx.x >> 6, lane = threadIdx.x & 63;
  int node = blockIdx.x*4 + wid;
  if (node >= NN) return;
  int chunk = lane & 7, epar = lane >> 3;
  int beg = rowptr[node], en = rowptr[node+1];
  float acc[8] = {0.f,0.f,0.f,0.f,0.f,0.f,0.f,0.f};
  if (epar == 0){
    uint4 q = *(const uint4*)&h[(size_t)node*NH + chunk*8];
    cv8(q, acc);
  }
  for (int j = beg + epar; j < en; j += 8){
    int src = csr[j];
    uint4 q = *(const uint4*)&h[(size_t)src*NH + chunk*8];
    float f[8]; cv8(q, f);
    #pragma unroll
    for (int i = 0; i < 8; i++) acc[i] += f[i];
  }
  #pragma unroll
  for (int i = 0; i < 8; i++){
    acc[i] += __shfl_xor(acc[i], 8);
    acc[i] += __shfl_xor(acc[i], 16);
    acc[i] += __shfl_xor(acc[i], 32);
  }
  if (epar == 0){
    float* dst = &U[(size_t)node*NH + chunk*8];
    float4 v0; v0.x=acc[0]; v0.y=acc[1]; v0.z=acc[2]; v0.w=acc[3];
    float4 v1; v1.x=acc[4]; v1.y=acc[5]; v1.z=acc[6]; v1.w=acc[7];
    *(float4*)&dst[0] = v0;
    *(float4*)&dst[4] = v1;
  }
}

// ---- transform: EXACT R5-proven inner loop, 32 rows/block (grid 2x) for occupancy
__global__ __launch_bounds__(256) void k_transform_f(const float* __restrict__ x,
    const float* __restrict__ Wt, const float* __restrict__ bt,
    float* __restrict__ t, float* __restrict__ s1, float* __restrict__ s2){
  __shared__ float sW[NF*NH];     // 32 KB [k][c]
  __shared__ float sRed[8*NH];
  int tid = threadIdx.x;
  for (int i = tid*4; i < NF*NH; i += 1024)
    *(float4*)&sW[i] = *(const float4*)(Wt + i);
  __syncthreads();
  int tx = tid & 63, ty = tid >> 6;
  int row0 = blockIdx.x*32 + ty*8;
  float b = bt[tx];
  float ls1 = 0.f, ls2 = 0.f;
  for (int i = 0; i < 8; i++){
    int row = row0 + i;
    if (row >= NN) break;
    const float4* xr = (const float4*)(x + (size_t)row*NF);
    float acc = b;
    #pragma unroll
    for (int k4 = 0; k4 < 32; k4++){
      float4 f = xr[k4];
      int kb = k4*4;
      acc += f.x*sW[(kb+0)*NH+tx];
      acc += f.y*sW[(kb+1)*NH+tx];
      acc += f.z*sW[(kb+2)*NH+tx];
      acc += f.w*sW[(kb+3)*NH+tx];
    }
    t[(size_t)row*NH + tx] = acc;
    ls1 += acc; ls2 += acc*acc;
  }
  sRed[ty*NH + tx] = ls1;
  sRed[(4+ty)*NH + tx] = ls2;
  __syncthreads();
  if (ty == 0){
    float a1 = sRed[tx] + sRed[NH+tx] + sRed[2*NH+tx] + sRed[3*NH+tx];
    float a2 = sRed[4*NH+tx] + sRed[5*NH+tx] + sRed[6*NH+tx] + sRed[7*NH+tx];
    unsafeAtomicAdd(&s1[tx], a1);
    unsafeAtomicAdd(&s2[tx], a2);
  }
}

// ---- per-graph embed with fused BN-fold; writes h as bf16 (gather is sole consumer)
__global__ __launch_bounds__(256) void k_embed(const float* __restrict__ t,
    const float* __restrict__ s1, const float* __restrict__ s2,
    const void* __restrict__ gamma, const void* __restrict__ beta, int ofs,
    u16* __restrict__ h, int write_h,
    const int* __restrict__ starts, const int* __restrict__ flag,
    void* __restrict__ dout, int layer){
  __shared__ float sRed[8*NH];
  int g = blockIdx.x;
  int tx = threadIdx.x & 63, ty = threadIdx.x >> 6;
  int bf = flag[0];
  float gm = bf ? bf1(((const u16*)gamma)[ofs+tx]) : ((const float*)gamma)[ofs+tx];
  float be = bf ? bf1(((const u16*)beta)[ofs+tx])  : ((const float*)beta)[ofs+tx];
  float mean = s1[tx] * (1.f/NN);
  float var  = s2[tx] * (1.f/NN) - mean*mean;
  float rr = rsqrtf(fmaxf(var, 0.f) + 1e-5f);
  float sc = gm * rr;
  float sh = be - mean*sc;
  int st = starts[g], en = starts[g+1];
  float ls1 = 0.f, ls2 = 0.f;
  if (write_h){
    for (int n = st + ty; n < en; n += 4){
      float z = t[(size_t)n*NH + tx] * sc + sh;
      h[(size_t)n*NH + tx] = f2b(z);
      ls1 += z; ls2 += z*z;
    }
  } else {
    for (int n = st + ty; n < en; n += 4){
      float z = t[(size_t)n*NH + tx] * sc + sh;
      ls1 += z; ls2 += z*z;
    }
  }
  sRed[ty*NH + tx] = ls1;
  sRed[(4+ty)*NH + tx] = ls2;
  __syncthreads();
  if (ty == 0){
    float a1 = sRed[tx] + sRed[NH+tx] + sRed[2*NH+tx] + sRed[3*NH+tx];
    float a2 = sRed[4*NH+tx] + sRed[5*NH+tx] + sRed[6*NH+tx] + sRed[7*NH+tx];
    int cnt = en - st;
    float inv = 1.f / (float)max(cnt, 1);
    float m = a1 * inv;
    float vv = a2 * inv - m*m;
    float s = sqrtf(fmaxf(vv, 0.f));
    size_t eidx = ((size_t)layer*NG + g)*NH + tx;
    size_t sidx = (size_t)4*NG*NH + eidx;
    if (bf){
      ((__hip_bfloat16*)dout)[eidx] = __float2bfloat16(m);
      ((__hip_bfloat16*)dout)[sidx] = __float2bfloat16(s);
    } else {
      ((float*)dout)[eidx] = m;
      ((float*)dout)[sidx] = s;
    }
  }
}

// ---- MLP (unchanged from R7): in-place relu(relu(U@W1)@W2), row-paired
__global__ __launch_bounds__(256) void k_mlp_f(float* __restrict__ U,
    const float* __restrict__ W1, const float* __restrict__ W2, int wofs,
    float* __restrict__ s1, float* __restrict__ s2){
  __shared__ float sU[64*NH];    // 16 KB
  __shared__ float sV[64*NH];    // 16 KB
  __shared__ float sW1[NH*NH];   // 16 KB (reused as reduction scratch)
  __shared__ float sW2[NH*NH];   // 16 KB
  int tid = threadIdx.x;
  for (int i = tid*4; i < NH*NH; i += 1024){
    *(float4*)&sW1[i] = *(const float4*)(W1 + wofs + i);
    *(float4*)&sW2[i] = *(const float4*)(W2 + wofs + i);
  }
  int node0 = blockIdx.x*64;
  int nrows = min(64, NN - node0);
  for (int i = tid; i < 1024; i += 256){
    int r = i >> 4, c4 = i & 15;
    float4 q;
    if (r < nrows) q = *(const float4*)&U[(size_t)(node0+r)*NH + c4*4];
    else { q.x=0.f; q.y=0.f; q.z=0.f; q.w=0.f; }
    *(float4*)&sU[r*NH + c4*4] = q;
  }
  __syncthreads();
  int tx = tid & 63, ty = tid >> 6;
  for (int i = 0; i < 8; i++){
    int ra = ty*16 + i, rb = ra + 8;
    const float4* ua = (const float4*)&sU[ra*NH];
    const float4* ub = (const float4*)&sU[rb*NH];
    float acca = 0.f, accb = 0.f;
    #pragma unroll
    for (int k4 = 0; k4 < 16; k4++){
      float4 a = ua[k4];
      float4 bq = ub[k4];
      float w0 = sW1[(k4*4+0)*NH+tx];
      float w1 = sW1[(k4*4+1)*NH+tx];
      float w2 = sW1[(k4*4+2)*NH+tx];
      float w3 = sW1[(k4*4+3)*NH+tx];
      acca += a.x*w0 + a.y*w1 + a.z*w2 + a.w*w3;
      accb += bq.x*w0 + bq.y*w1 + bq.z*w2 + bq.w*w3;
    }
    sV[ra*NH + tx] = fmaxf(acca, 0.f);
    sV[rb*NH + tx] = fmaxf(accb, 0.f);
  }
  __syncthreads();
  float ls1 = 0.f, ls2 = 0.f;
  for (int i = 0; i < 8; i++){
    int ra = ty*16 + i, rb = ra + 8;
    const float4* va = (const float4*)&sV[ra*NH];
    const float4* vb = (const float4*)&sV[rb*NH];
    float acca = 0.f, accb = 0.f;
    #pragma unroll
    for (int k4 = 0; k4 < 16; k4++){
      float4 a = va[k4];
      float4 bq = vb[k4];
      float w0 = sW2[(k4*4+0)*NH+tx];
      float w1 = sW2[(k4*4+1)*NH+tx];
      float w2 = sW2[(k4*4+2)*NH+tx];
      float w3 = sW2[(k4*4+3)*NH+tx];
      acca += a.x*w0 + a.y*w1 + a.z*w2 + a.w*w3;
      accb += bq.x*w0 + bq.y*w1 + bq.z*w2 + bq.w*w3;
    }
    float ta = fmaxf(acca, 0.f), tb = fmaxf(accb, 0.f);
    if (ra < nrows){ U[(size_t)(node0+ra)*NH + tx] = ta; ls1 += ta; ls2 += ta*ta; }
    if (rb < nrows){ U[(size_t)(node0+rb)*NH + tx] = tb; ls1 += tb; ls2 += tb*tb; }
  }
  __syncthreads();
  sW1[ty*NH + tx] = ls1;
  sW1[(4+ty)*NH + tx] = ls2;
  __syncthreads();
  if (ty == 0){
    float a1 = sW1[tx] + sW1[NH+tx] + sW1[2*NH+tx] + sW1[3*NH+tx];
    float a2 = sW1[4*NH+tx] + sW1[5*NH+tx] + sW1[6*NH+tx] + sW1[7*NH+tx];
    unsafeAtomicAdd(&s1[tx], a1);
    unsafeAtomicAdd(&s2[tx], a2);
  }
}

extern "C" void kernel_launch(void* const* d_in, const int* in_sizes, int n_in,
                              void* d_out, int out_size, void* d_ws, size_t ws_size,
                              hipStream_t stream) {
  const void* x    = d_in[0];
  const int* ei    = (const int*)d_in[1];
  const int* batch = (const int*)d_in[2];
  const void* Wt   = d_in[3];
  const void* bt   = d_in[4];
  const void* g0   = d_in[5];
  const void* b0   = d_in[6];
  const void* W1   = d_in[7];
  const void* W2   = d_in[8];
  const void* gs   = d_in[9];
  const void* bs   = d_in[10];

  u16*  hbuf = (u16*)d_ws;                      // NN*NH bf16 (in NN*NH*4-byte slot)
  float* ubuf = (float*)d_ws + (size_t)NN*NH;   // NN*NH f32 (U, then in-place T)
  float* s1   = ubuf + (size_t)NN*NH;           // 64
  float* s2   = s1 + NH;                        // 64 (contiguous after s1)
  float* pad  = s2 + NH;                        // 128 (layout spacer)
  int* starts = (int*)(pad + 2*NH);             // 512
  int* flag   = starts + 512;                   // 64 (padded)
  int* deg    = flag + 64;                      // NN
  int* rowptr = deg + NN;                       // NN+64
  int* cursor = rowptr + NN + 64;               // NN
  int* csr    = cursor + NN;                    // NE
  int* bsum   = csr + NE;                       // 256

  hipMemsetAsync(s1, 0, 2*NH*sizeof(float), stream);
  hipMemsetAsync(deg, 0, NN*sizeof(int), stream);
  k_detect<<<1, 64, 0, stream>>>((const u32*)x, flag);
  k_bounds<<<1, 512, 0, stream>>>(batch, starts);
  k_count<<<(NE+255)/256, 256, 0, stream>>>(ei, deg);
  k_scanA<<<SCAN_B, 256, 0, stream>>>(deg, bsum);
  k_scanB<<<1, 256, 0, stream>>>(bsum);
  k_scanC<<<SCAN_B, 256, 0, stream>>>(deg, bsum, rowptr, cursor);
  k_fill<<<(NE+255)/256, 256, 0, stream>>>(ei, cursor, csr);

  k_transform_f<<<(NN+31)/32, 256, 0, stream>>>((const float*)x, (const float*)Wt, (const float*)bt, ubuf, s1, s2);
  k_embed<<<NG, 256, 0, stream>>>(ubuf, s1, s2, g0, b0, 0, hbuf, 1, starts, flag, d_out, 0);

  for (int l = 0; l < 3; l++){
    k_gather<<<(NN+3)/4, 256, 0, stream>>>(hbuf, rowptr, csr, ubuf, s1);  // also zeros s1/s2
    k_mlp_f<<<(NN+63)/64, 256, 0, stream>>>(ubuf, (const float*)W1, (const float*)W2, l*NH*NH, s1, s2);
    k_embed<<<NG, 256, 0, stream>>>(ubuf, s1, s2, gs, bs, l*NH, hbuf, (l < 2) ? 1 : 0, starts, flag, d_out, l+1);
  }
}

// Round 10
// 460.818 us; speedup vs baseline: 3.5608x; 1.1077x over previous
//
#include <hip/hip_runtime.h>
#include <hip/hip_bf16.h>

#define NN 50000
#define NE 800000
#define NG 500
#define NF 128
#define NH 64
#define SCAN_B ((NN + 255)/256)   // 196

typedef unsigned int u32;
typedef unsigned short u16;
typedef _Float16 h2 __attribute__((ext_vector_type(2)));

__device__ __forceinline__ float bf1(u16 v){ return __uint_as_float(((u32)v) << 16); }

__device__ __forceinline__ float fdot2(h2 a, h2 b, float c){
#if __has_builtin(__builtin_amdgcn_fdot2)
  return __builtin_amdgcn_fdot2(a, b, c, false);
#else
  return c + (float)a.x*(float)b.x + (float)a.y*(float)b.y;
#endif
}
__device__ __forceinline__ u32 pk(float a, float b){
  return __builtin_bit_cast(u32, __builtin_amdgcn_cvt_pkrtz(a, b));
}
__device__ __forceinline__ h2 uph(u32 u){ return __builtin_bit_cast(h2, u); }
__device__ __forceinline__ u16 f16b(float f){ return __builtin_bit_cast(u16, (_Float16)f); }

// decode 8 f16 -> 8 f32
__device__ __forceinline__ void cv8h(uint4 q, float* f){
  h2 v0 = uph(q.x), v1 = uph(q.y), v2 = uph(q.z), v3 = uph(q.w);
  f[0]=(float)v0.x; f[1]=(float)v0.y; f[2]=(float)v1.x; f[3]=(float)v1.y;
  f[4]=(float)v2.x; f[5]=(float)v2.y; f[6]=(float)v3.x; f[7]=(float)v3.y;
}

// ---- dtype probe (f32 inputs proven; kept as output-format hedge)
__global__ void k_detect(const u32* __restrict__ x, int* __restrict__ flag){
  int lane = threadIdx.x;
  u32 w = x[lane];
  u32 lo = w & 0xFFFFu;
  u32 e = (lo >> 7) & 0xFFu;
  bool vote = (e >= 0x60u && e <= 0x8Fu);
  unsigned long long m = __ballot(vote);
  if (lane == 0) flag[0] = (__popcll(m) >= 32) ? 1 : 0;
}

// ---- graph boundaries
__global__ void k_bounds(const int* __restrict__ batch, int* __restrict__ starts){
  int g = threadIdx.x;
  if (g > NG) return;
  int lo = 0, hi = NN;
  while (lo < hi){ int mid = (lo + hi) >> 1; if (batch[mid] < g) lo = mid + 1; else hi = mid; }
  starts[g] = lo;
}

// ---- CSR build: degree count
__global__ __launch_bounds__(256) void k_count(const int* __restrict__ ei, int* __restrict__ deg){
  int e = blockIdx.x*256 + threadIdx.x;
  if (e >= NE) return;
  atomicAdd(&deg[ei[NE + e]], 1);
}

// ---- hierarchical coalesced scan (3 phases)
__global__ __launch_bounds__(256) void k_scanA(const int* __restrict__ deg, int* __restrict__ bsum){
  __shared__ int red[256];
  int t = threadIdx.x;
  int i = blockIdx.x*256 + t;
  red[t] = (i < NN) ? deg[i] : 0;
  __syncthreads();
  for (int off = 128; off > 0; off >>= 1){
    if (t < off) red[t] += red[t+off];
    __syncthreads();
  }
  if (t == 0) bsum[blockIdx.x] = red[0];
}

__global__ __launch_bounds__(256) void k_scanB(int* __restrict__ bsum){
  __shared__ int part[256];
  int t = threadIdx.x;
  int v = (t < SCAN_B) ? bsum[t] : 0;
  part[t] = v;
  __syncthreads();
  for (int off = 1; off < 256; off <<= 1){
    int u = (t >= off) ? part[t-off] : 0;
    __syncthreads();
    part[t] += u;
    __syncthreads();
  }
  if (t < SCAN_B) bsum[t] = part[t] - v;   // exclusive
}

__global__ __launch_bounds__(256) void k_scanC(const int* __restrict__ deg, const int* __restrict__ bsum,
    int* __restrict__ rowptr, int* __restrict__ cursor){
  __shared__ int part[256];
  int t = threadIdx.x;
  int i = blockIdx.x*256 + t;
  int v = (i < NN) ? deg[i] : 0;
  part[t] = v;
  __syncthreads();
  for (int off = 1; off < 256; off <<= 1){
    int u = (t >= off) ? part[t-off] : 0;
    __syncthreads();
    part[t] += u;
    __syncthreads();
  }
  int ex = part[t] - v + bsum[blockIdx.x];
  if (i < NN){ rowptr[i] = ex; cursor[i] = ex; }
  if (blockIdx.x == 0 && t == 0) rowptr[NN] = NE;
}

// ---- CSR fill
__global__ __launch_bounds__(256) void k_fill(const int* __restrict__ ei,
    int* __restrict__ cursor, int* __restrict__ csr){
  int e = blockIdx.x*256 + threadIdx.x;
  if (e >= NE) return;
  int dst = ei[NE + e];
  int slot = atomicAdd(&cursor[dst], 1);
  csr[slot] = ei[e];
}

// ---- gather (f16 h): U[node] = h[node] + sum_{src} h[src]; block 0 re-zeros s1/s2
__global__ __launch_bounds__(256) void k_gather(const u16* __restrict__ h,
    const int* __restrict__ rowptr, const int* __restrict__ csr, float* __restrict__ U,
    float* __restrict__ s1){
  if (blockIdx.x == 0 && threadIdx.x < 128) s1[threadIdx.x] = 0.f;  // s1[0:64], s2[64:128]
  int wid = threadIdx.x >> 6, lane = threadIdx.x & 63;
  int node = blockIdx.x*4 + wid;
  if (node >= NN) return;
  int chunk = lane & 7, epar = lane >> 3;
  int beg = rowptr[node], en = rowptr[node+1];
  float acc[8] = {0.f,0.f,0.f,0.f,0.f,0.f,0.f,0.f};
  if (epar == 0){
    uint4 q = *(const uint4*)&h[(size_t)node*NH + chunk*8];
    cv8h(q, acc);
  }
  for (int j = beg + epar; j < en; j += 8){
    int src = csr[j];
    uint4 q = *(const uint4*)&h[(size_t)src*NH + chunk*8];
    float f[8]; cv8h(q, f);
    #pragma unroll
    for (int i = 0; i < 8; i++) acc[i] += f[i];
  }
  #pragma unroll
  for (int i = 0; i < 8; i++){
    acc[i] += __shfl_xor(acc[i], 8);
    acc[i] += __shfl_xor(acc[i], 16);
    acc[i] += __shfl_xor(acc[i], 32);
  }
  if (epar == 0){
    float* dst = &U[(size_t)node*NH + chunk*8];
    float4 v0; v0.x=acc[0]; v0.y=acc[1]; v0.z=acc[2]; v0.w=acc[3];
    float4 v1; v1.x=acc[4]; v1.y=acc[5]; v1.z=acc[6]; v1.w=acc[7];
    *(float4*)&dst[0] = v0;
    *(float4*)&dst[4] = v1;
  }
}

// ---- transform: R8 skeleton, f16-packed weights + fdot2 (halves LDS+MAC issue)
__global__ __launch_bounds__(256) void k_transform_f(const float* __restrict__ x,
    const float* __restrict__ Wt, const float* __restrict__ bt,
    float* __restrict__ t, float* __restrict__ s1, float* __restrict__ s2){
  __shared__ u32 sWh[64*64];      // 16 KB: half2(W[2k2][c], W[2k2+1][c]) at [k2][c]
  __shared__ float sRed[8*NH];
  int tid = threadIdx.x;
  for (int i = tid; i < 1024; i += 256){
    int k2 = i >> 4, c4 = i & 15;
    float4 a = *(const float4*)(Wt + (size_t)(2*k2)*NH + c4*4);
    float4 b = *(const float4*)(Wt + (size_t)(2*k2+1)*NH + c4*4);
    uint4 st;
    st.x = pk(a.x, b.x); st.y = pk(a.y, b.y); st.z = pk(a.z, b.z); st.w = pk(a.w, b.w);
    *(uint4*)&sWh[k2*64 + c4*4] = st;
  }
  __syncthreads();
  int tx = tid & 63, ty = tid >> 6;
  int row0 = blockIdx.x*32 + ty*8;
  float b = bt[tx];
  float ls1 = 0.f, ls2 = 0.f;
  for (int i = 0; i < 8; i++){
    int row = row0 + i;
    if (row >= NN) break;
    const float4* xr = (const float4*)(x + (size_t)row*NF);
    float acc = b;
    #pragma unroll
    for (int k4 = 0; k4 < 32; k4++){
      float4 f = xr[k4];
      h2 a01 = uph(pk(f.x, f.y));
      h2 a23 = uph(pk(f.z, f.w));
      h2 w01 = uph(sWh[(2*k4)*64 + tx]);
      h2 w23 = uph(sWh[(2*k4+1)*64 + tx]);
      acc = fdot2(a01, w01, acc);
      acc = fdot2(a23, w23, acc);
    }
    t[(size_t)row*NH + tx] = acc;
    ls1 += acc; ls2 += acc*acc;
  }
  sRed[ty*NH + tx] = ls1;
  sRed[(4+ty)*NH + tx] = ls2;
  __syncthreads();
  if (ty == 0){
    float a1 = sRed[tx] + sRed[NH+tx] + sRed[2*NH+tx] + sRed[3*NH+tx];
    float a2 = sRed[4*NH+tx] + sRed[5*NH+tx] + sRed[6*NH+tx] + sRed[7*NH+tx];
    unsafeAtomicAdd(&s1[tx], a1);
    unsafeAtomicAdd(&s2[tx], a2);
  }
}

// ---- per-graph embed with fused BN-fold; writes h as f16 (gather is sole consumer)
__global__ __launch_bounds__(256) void k_embed(const float* __restrict__ t,
    const float* __restrict__ s1, const float* __restrict__ s2,
    const void* __restrict__ gamma, const void* __restrict__ beta, int ofs,
    u16* __restrict__ h, int write_h,
    const int* __restrict__ starts, const int* __restrict__ flag,
    void* __restrict__ dout, int layer){
  __shared__ float sRed[8*NH];
  int g = blockIdx.x;
  int tx = threadIdx.x & 63, ty = threadIdx.x >> 6;
  int bf = flag[0];
  float gm = bf ? bf1(((const u16*)gamma)[ofs+tx]) : ((const float*)gamma)[ofs+tx];
  float be = bf ? bf1(((const u16*)beta)[ofs+tx])  : ((const float*)beta)[ofs+tx];
  float mean = s1[tx] * (1.f/NN);
  float var  = s2[tx] * (1.f/NN) - mean*mean;
  float rr = rsqrtf(fmaxf(var, 0.f) + 1e-5f);
  float sc = gm * rr;
  float sh = be - mean*sc;
  int st = starts[g], en = starts[g+1];
  float ls1 = 0.f, ls2 = 0.f;
  if (write_h){
    for (int n = st + ty; n < en; n += 4){
      float z = t[(size_t)n*NH + tx] * sc + sh;
      h[(size_t)n*NH + tx] = f16b(z);
      ls1 += z; ls2 += z*z;
    }
  } else {
    for (int n = st + ty; n < en; n += 4){
      float z = t[(size_t)n*NH + tx] * sc + sh;
      ls1 += z; ls2 += z*z;
    }
  }
  sRed[ty*NH + tx] = ls1;
  sRed[(4+ty)*NH + tx] = ls2;
  __syncthreads();
  if (ty == 0){
    float a1 = sRed[tx] + sRed[NH+tx] + sRed[2*NH+tx] + sRed[3*NH+tx];
    float a2 = sRed[4*NH+tx] + sRed[5*NH+tx] + sRed[6*NH+tx] + sRed[7*NH+tx];
    int cnt = en - st;
    float inv = 1.f / (float)max(cnt, 1);
    float m = a1 * inv;
    float vv = a2 * inv - m*m;
    float s = sqrtf(fmaxf(vv, 0.f));
    size_t eidx = ((size_t)layer*NG + g)*NH + tx;
    size_t sidx = (size_t)4*NG*NH + eidx;
    if (bf){
      ((__hip_bfloat16*)dout)[eidx] = __float2bfloat16(m);
      ((__hip_bfloat16*)dout)[sidx] = __float2bfloat16(s);
    } else {
      ((float*)dout)[eidx] = m;
      ((float*)dout)[sidx] = s;
    }
  }
}

// ---- MLP: R8 skeleton, f16 staging + f16-packed weights + fdot2, row-paired
__global__ __launch_bounds__(256) void k_mlp_f(float* __restrict__ U,
    const float* __restrict__ W1, const float* __restrict__ W2, int wofs,
    float* __restrict__ s1, float* __restrict__ s2){
  __shared__ u32 sW1h[32*64];   // 8 KB: half2(W[2k2][c], W[2k2+1][c])
  __shared__ u32 sW2h[32*64];   // 8 KB
  __shared__ u16 sUh[64*64];    // 8 KB f16 rows
  __shared__ u16 sVh[64*64];    // 8 KB
  __shared__ float sRed[8*NH];  // 2 KB
  int tid = threadIdx.x;
  for (int i = tid; i < 512; i += 256){
    int k2 = i >> 4, c4 = i & 15;
    float4 a1 = *(const float4*)(W1 + wofs + (size_t)(2*k2)*NH + c4*4);
    float4 b1 = *(const float4*)(W1 + wofs + (size_t)(2*k2+1)*NH + c4*4);
    uint4 s;
    s.x = pk(a1.x, b1.x); s.y = pk(a1.y, b1.y); s.z = pk(a1.z, b1.z); s.w = pk(a1.w, b1.w);
    *(uint4*)&sW1h[k2*64 + c4*4] = s;
    float4 a2 = *(const float4*)(W2 + wofs + (size_t)(2*k2)*NH + c4*4);
    float4 b2 = *(const float4*)(W2 + wofs + (size_t)(2*k2+1)*NH + c4*4);
    uint4 s2v;
    s2v.x = pk(a2.x, b2.x); s2v.y = pk(a2.y, b2.y); s2v.z = pk(a2.z, b2.z); s2v.w = pk(a2.w, b2.w);
    *(uint4*)&sW2h[k2*64 + c4*4] = s2v;
  }
  int node0 = blockIdx.x*64;
  int nrows = min(64, NN - node0);
  for (int i = tid; i < 1024; i += 256){
    int r = i >> 4, c4 = i & 15;
    float4 q;
    if (r < nrows) q = *(const float4*)&U[(size_t)(node0+r)*NH + c4*4];
    else { q.x=0.f; q.y=0.f; q.z=0.f; q.w=0.f; }
    uint2 w; w.x = pk(q.x, q.y); w.y = pk(q.z, q.w);
    *(uint2*)&sUh[r*64 + c4*4] = w;
  }
  __syncthreads();
  int tx = tid & 63, ty = tid >> 6;
  // phase A: V = relu(U @ W1)
  for (int i = 0; i < 8; i++){
    int ra = ty*16 + i, rb = ra + 8;
    float acca = 0.f, accb = 0.f;
    #pragma unroll
    for (int k8 = 0; k8 < 8; k8++){
      uint4 ua = *(const uint4*)&sUh[ra*64 + k8*8];
      uint4 ub = *(const uint4*)&sUh[rb*64 + k8*8];
      h2 w0 = uph(sW1h[(k8*4+0)*64 + tx]);
      h2 w1 = uph(sW1h[(k8*4+1)*64 + tx]);
      h2 w2 = uph(sW1h[(k8*4+2)*64 + tx]);
      h2 w3 = uph(sW1h[(k8*4+3)*64 + tx]);
      acca = fdot2(uph(ua.x), w0, acca); accb = fdot2(uph(ub.x), w0, accb);
      acca = fdot2(uph(ua.y), w1, acca); accb = fdot2(uph(ub.y), w1, accb);
      acca = fdot2(uph(ua.z), w2, acca); accb = fdot2(uph(ub.z), w2, accb);
      acca = fdot2(uph(ua.w), w3, acca); accb = fdot2(uph(ub.w), w3, accb);
    }
    sVh[ra*64 + tx] = f16b(fmaxf(acca, 0.f));
    sVh[rb*64 + tx] = f16b(fmaxf(accb, 0.f));
  }
  __syncthreads();
  // phase B: T = relu(V @ W2), in-place to U
  float ls1 = 0.f, ls2 = 0.f;
  for (int i = 0; i < 8; i++){
    int ra = ty*16 + i, rb = ra + 8;
    float acca = 0.f, accb = 0.f;
    #pragma unroll
    for (int k8 = 0; k8 < 8; k8++){
      uint4 va = *(const uint4*)&sVh[ra*64 + k8*8];
      uint4 vb = *(const uint4*)&sVh[rb*64 + k8*8];
      h2 w0 = uph(sW2h[(k8*4+0)*64 + tx]);
      h2 w1 = uph(sW2h[(k8*4+1)*64 + tx]);
      h2 w2 = uph(sW2h[(k8*4+2)*64 + tx]);
      h2 w3 = uph(sW2h[(k8*4+3)*64 + tx]);
      acca = fdot2(uph(va.x), w0, acca); accb = fdot2(uph(vb.x), w0, accb);
      acca = fdot2(uph(va.y), w1, acca); accb = fdot2(uph(vb.y), w1, accb);
      acca = fdot2(uph(va.z), w2, acca); accb = fdot2(uph(vb.z), w2, accb);
      acca = fdot2(uph(va.w), w3, acca); accb = fdot2(uph(vb.w), w3, accb);
    }
    float ta = fmaxf(acca, 0.f), tb = fmaxf(accb, 0.f);
    if (ra < nrows){ U[(size_t)(node0+ra)*NH + tx] = ta; ls1 += ta; ls2 += ta*ta; }
    if (rb < nrows){ U[(size_t)(node0+rb)*NH + tx] = tb; ls1 += tb; ls2 += tb*tb; }
  }
  __syncthreads();
  sRed[ty*NH + tx] = ls1;
  sRed[(4+ty)*NH + tx] = ls2;
  __syncthreads();
  if (ty == 0){
    float a1 = sRed[tx] + sRed[NH+tx] + sRed[2*NH+tx] + sRed[3*NH+tx];
    float a2 = sRed[4*NH+tx] + sRed[5*NH+tx] + sRed[6*NH+tx] + sRed[7*NH+tx];
    unsafeAtomicAdd(&s1[tx], a1);
    unsafeAtomicAdd(&s2[tx], a2);
  }
}

extern "C" void kernel_launch(void* const* d_in, const int* in_sizes, int n_in,
                              void* d_out, int out_size, void* d_ws, size_t ws_size,
                              hipStream_t stream) {
  const void* x    = d_in[0];
  const int* ei    = (const int*)d_in[1];
  const int* batch = (const int*)d_in[2];
  const void* Wt   = d_in[3];
  const void* bt   = d_in[4];
  const void* g0   = d_in[5];
  const void* b0   = d_in[6];
  const void* W1   = d_in[7];
  const void* W2   = d_in[8];
  const void* gs   = d_in[9];
  const void* bs   = d_in[10];

  u16*  hbuf = (u16*)d_ws;                      // NN*NH f16 (in NN*NH*4-byte slot)
  float* ubuf = (float*)d_ws + (size_t)NN*NH;   // NN*NH f32 (U, then in-place T)
  float* s1   = ubuf + (size_t)NN*NH;           // 64
  float* s2   = s1 + NH;                        // 64 (contiguous after s1)
  float* pad  = s2 + NH;                        // 128 (layout spacer)
  int* starts = (int*)(pad + 2*NH);             // 512
  int* flag   = starts + 512;                   // 64 (padded)
  int* deg    = flag + 64;                      // NN
  int* rowptr = deg + NN;                       // NN+64
  int* cursor = rowptr + NN + 64;               // NN
  int* csr    = cursor + NN;                    // NE
  int* bsum   = csr + NE;                       // 256

  hipMemsetAsync(s1, 0, 2*NH*sizeof(float), stream);
  hipMemsetAsync(deg, 0, NN*sizeof(int), stream);
  k_detect<<<1, 64, 0, stream>>>((const u32*)x, flag);
  k_bounds<<<1, 512, 0, stream>>>(batch, starts);
  k_count<<<(NE+255)/256, 256, 0, stream>>>(ei, deg);
  k_scanA<<<SCAN_B, 256, 0, stream>>>(deg, bsum);
  k_scanB<<<1, 256, 0, stream>>>(bsum);
  k_scanC<<<SCAN_B, 256, 0, stream>>>(deg, bsum, rowptr, cursor);
  k_fill<<<(NE+255)/256, 256, 0, stream>>>(ei, cursor, csr);

  k_transform_f<<<(NN+31)/32, 256, 0, stream>>>((const float*)x, (const float*)Wt, (const float*)bt, ubuf, s1, s2);
  k_embed<<<NG, 256, 0, stream>>>(ubuf, s1, s2, g0, b0, 0, hbuf, 1, starts, flag, d_out, 0);

  for (int l = 0; l < 3; l++){
    k_gather<<<(NN+3)/4, 256, 0, stream>>>(hbuf, rowptr, csr, ubuf, s1);  // also zeros s1/s2
    k_mlp_f<<<(NN+63)/64, 256, 0, stream>>>(ubuf, (const float*)W1, (const float*)W2, l*NH*NH, s1, s2);
    k_embed<<<NG, 256, 0, stream>>>(ubuf, s1, s2, gs, bs, l*NH, hbuf, (l < 2) ? 1 : 0, starts, flag, d_out, l+1);
  }
}

// Round 11
// 451.068 us; speedup vs baseline: 3.6377x; 1.0216x over previous
//
#include <hip/hip_runtime.h>
#include <hip/hip_bf16.h>

#define NN 50000
#define NE 800000
#define NG 500
#define NF 128
#define NH 64
#define SCAN_B ((NN + 255)/256)   // 196

typedef unsigned int u32;
typedef unsigned short u16;
typedef _Float16 h2 __attribute__((ext_vector_type(2)));

__device__ __forceinline__ float bf1(u16 v){ return __uint_as_float(((u32)v) << 16); }

__device__ __forceinline__ float fdot2(h2 a, h2 b, float c){
#if __has_builtin(__builtin_amdgcn_fdot2)
  return __builtin_amdgcn_fdot2(a, b, c, false);
#else
  return c + (float)a.x*(float)b.x + (float)a.y*(float)b.y;
#endif
}
__device__ __forceinline__ u32 pk(float a, float b){
  return __builtin_bit_cast(u32, __builtin_amdgcn_cvt_pkrtz(a, b));
}
__device__ __forceinline__ h2 uph(u32 u){ return __builtin_bit_cast(h2, u); }
__device__ __forceinline__ u16 f16b(float f){ return __builtin_bit_cast(u16, (_Float16)f); }

// decode 8 f16 -> 8 f32
__device__ __forceinline__ void cv8h(uint4 q, float* f){
  h2 v0 = uph(q.x), v1 = uph(q.y), v2 = uph(q.z), v3 = uph(q.w);
  f[0]=(float)v0.x; f[1]=(float)v0.y; f[2]=(float)v1.x; f[3]=(float)v1.y;
  f[4]=(float)v2.x; f[5]=(float)v2.y; f[6]=(float)v3.x; f[7]=(float)v3.y;
}

// ---- dtype probe (f32 inputs proven; kept as output-format hedge)
__global__ void k_detect(const u32* __restrict__ x, int* __restrict__ flag){
  int lane = threadIdx.x;
  u32 w = x[lane];
  u32 lo = w & 0xFFFFu;
  u32 e = (lo >> 7) & 0xFFu;
  bool vote = (e >= 0x60u && e <= 0x8Fu);
  unsigned long long m = __ballot(vote);
  if (lane == 0) flag[0] = (__popcll(m) >= 32) ? 1 : 0;
}

// ---- graph boundaries
__global__ void k_bounds(const int* __restrict__ batch, int* __restrict__ starts){
  int g = threadIdx.x;
  if (g > NG) return;
  int lo = 0, hi = NN;
  while (lo < hi){ int mid = (lo + hi) >> 1; if (batch[mid] < g) lo = mid + 1; else hi = mid; }
  starts[g] = lo;
}

// ---- CSR build: degree count
__global__ __launch_bounds__(256) void k_count(const int* __restrict__ ei, int* __restrict__ deg){
  int e = blockIdx.x*256 + threadIdx.x;
  if (e >= NE) return;
  atomicAdd(&deg[ei[NE + e]], 1);
}

// ---- hierarchical coalesced scan (3 phases)
__global__ __launch_bounds__(256) void k_scanA(const int* __restrict__ deg, int* __restrict__ bsum){
  __shared__ int red[256];
  int t = threadIdx.x;
  int i = blockIdx.x*256 + t;
  red[t] = (i < NN) ? deg[i] : 0;
  __syncthreads();
  for (int off = 128; off > 0; off >>= 1){
    if (t < off) red[t] += red[t+off];
    __syncthreads();
  }
  if (t == 0) bsum[blockIdx.x] = red[0];
}

__global__ __launch_bounds__(256) void k_scanB(int* __restrict__ bsum){
  __shared__ int part[256];
  int t = threadIdx.x;
  int v = (t < SCAN_B) ? bsum[t] : 0;
  part[t] = v;
  __syncthreads();
  for (int off = 1; off < 256; off <<= 1){
    int u = (t >= off) ? part[t-off] : 0;
    __syncthreads();
    part[t] += u;
    __syncthreads();
  }
  if (t < SCAN_B) bsum[t] = part[t] - v;   // exclusive
}

__global__ __launch_bounds__(256) void k_scanC(const int* __restrict__ deg, const int* __restrict__ bsum,
    int* __restrict__ rowptr, int* __restrict__ cursor){
  __shared__ int part[256];
  int t = threadIdx.x;
  int i = blockIdx.x*256 + t;
  int v = (i < NN) ? deg[i] : 0;
  part[t] = v;
  __syncthreads();
  for (int off = 1; off < 256; off <<= 1){
    int u = (t >= off) ? part[t-off] : 0;
    __syncthreads();
    part[t] += u;
    __syncthreads();
  }
  int ex = part[t] - v + bsum[blockIdx.x];
  if (i < NN){ rowptr[i] = ex; cursor[i] = ex; }
  if (blockIdx.x == 0 && t == 0) rowptr[NN] = NE;
}

// ---- CSR fill
__global__ __launch_bounds__(256) void k_fill(const int* __restrict__ ei,
    int* __restrict__ cursor, int* __restrict__ csr){
  int e = blockIdx.x*256 + threadIdx.x;
  if (e >= NE) return;
  int dst = ei[NE + e];
  int slot = atomicAdd(&cursor[dst], 1);
  csr[slot] = ei[e];
}

// ---- gather (f16 h): U[node] = h[node] + sum_{src} h[src]; block 0 re-zeros s1/s2
__global__ __launch_bounds__(256) void k_gather(const u16* __restrict__ h,
    const int* __restrict__ rowptr, const int* __restrict__ csr, float* __restrict__ U,
    float* __restrict__ s1){
  if (blockIdx.x == 0 && threadIdx.x < 128) s1[threadIdx.x] = 0.f;  // s1[0:64], s2[64:128]
  int wid = threadIdx.x >> 6, lane = threadIdx.x & 63;
  int node = blockIdx.x*4 + wid;
  if (node >= NN) return;
  int chunk = lane & 7, epar = lane >> 3;
  int beg = rowptr[node], en = rowptr[node+1];
  float acc[8] = {0.f,0.f,0.f,0.f,0.f,0.f,0.f,0.f};
  if (epar == 0){
    uint4 q = *(const uint4*)&h[(size_t)node*NH + chunk*8];
    cv8h(q, acc);
  }
  for (int j = beg + epar; j < en; j += 8){
    int src = csr[j];
    uint4 q = *(const uint4*)&h[(size_t)src*NH + chunk*8];
    float f[8]; cv8h(q, f);
    #pragma unroll
    for (int i = 0; i < 8; i++) acc[i] += f[i];
  }
  #pragma unroll
  for (int i = 0; i < 8; i++){
    acc[i] += __shfl_xor(acc[i], 8);
    acc[i] += __shfl_xor(acc[i], 16);
    acc[i] += __shfl_xor(acc[i], 32);
  }
  if (epar == 0){
    float* dst = &U[(size_t)node*NH + chunk*8];
    float4 v0; v0.x=acc[0]; v0.y=acc[1]; v0.z=acc[2]; v0.w=acc[3];
    float4 v1; v1.x=acc[4]; v1.y=acc[5]; v1.z=acc[6]; v1.w=acc[7];
    *(float4*)&dst[0] = v0;
    *(float4*)&dst[4] = v1;
  }
}

// ---- transform: LDS-staged x tile (kills global-latency stalls) + f16 fdot2, 2 acc chains
__global__ __launch_bounds__(256) void k_transform_f(const float* __restrict__ x,
    const float* __restrict__ Wt, const float* __restrict__ bt,
    float* __restrict__ t, float* __restrict__ s1, float* __restrict__ s2){
  __shared__ u32 sWh[64*64];      // 16 KB: half2(W[2k2][c], W[2k2+1][c]) at [k2][c]
  __shared__ u32 sXh[32*64];      // 8 KB: half2(x[r][2k2], x[r][2k2+1]) at [r][k2]
  __shared__ float sRed[8*NH];
  int tid = threadIdx.x;
  // stage weights f16-packed (per-lane coalesced float4 reads)
  for (int i = tid; i < 1024; i += 256){
    int k2 = i >> 4, c4 = i & 15;
    float4 a = *(const float4*)(Wt + (size_t)(2*k2)*NH + c4*4);
    float4 b = *(const float4*)(Wt + (size_t)(2*k2+1)*NH + c4*4);
    uint4 st;
    st.x = pk(a.x, b.x); st.y = pk(a.y, b.y); st.z = pk(a.z, b.z); st.w = pk(a.w, b.w);
    *(uint4*)&sWh[k2*64 + c4*4] = st;
  }
  // stage x tile: 32 rows x 128 f32, coalesced float2 per thread, packed to f16
  int row0 = blockIdx.x*32;
  for (int i = tid; i < 2048; i += 256){
    int r = i >> 6, k2 = i & 63;
    int row = row0 + r;
    float2 v;
    if (row < NN) v = *(const float2*)(x + (size_t)row*NF + 2*k2);
    else { v.x = 0.f; v.y = 0.f; }
    sXh[r*64 + k2] = pk(v.x, v.y);
  }
  __syncthreads();
  int tx = tid & 63, ty = tid >> 6;
  float b = bt[tx];
  float ls1 = 0.f, ls2 = 0.f;
  for (int i = 0; i < 8; i++){
    int r = ty*8 + i;
    int row = row0 + r;
    if (row >= NN) break;
    float acc0 = b, acc1 = 0.f;
    #pragma unroll
    for (int k2 = 0; k2 < 64; k2 += 2){
      uint2 xv = *(const uint2*)&sXh[r*64 + k2];    // wave-uniform b64 (broadcast)
      acc0 = fdot2(uph(xv.x), uph(sWh[k2*64 + tx]), acc0);
      acc1 = fdot2(uph(xv.y), uph(sWh[(k2+1)*64 + tx]), acc1);
    }
    float acc = acc0 + acc1;
    t[(size_t)row*NH + tx] = acc;
    ls1 += acc; ls2 += acc*acc;
  }
  sRed[ty*NH + tx] = ls1;
  sRed[(4+ty)*NH + tx] = ls2;
  __syncthreads();
  if (ty == 0){
    float a1 = sRed[tx] + sRed[NH+tx] + sRed[2*NH+tx] + sRed[3*NH+tx];
    float a2 = sRed[4*NH+tx] + sRed[5*NH+tx] + sRed[6*NH+tx] + sRed[7*NH+tx];
    unsafeAtomicAdd(&s1[tx], a1);
    unsafeAtomicAdd(&s2[tx], a2);
  }
}

// ---- per-graph embed with fused BN-fold; writes h as f16 (gather is sole consumer)
__global__ __launch_bounds__(256) void k_embed(const float* __restrict__ t,
    const float* __restrict__ s1, const float* __restrict__ s2,
    const void* __restrict__ gamma, const void* __restrict__ beta, int ofs,
    u16* __restrict__ h, int write_h,
    const int* __restrict__ starts, const int* __restrict__ flag,
    void* __restrict__ dout, int layer){
  __shared__ float sRed[8*NH];
  int g = blockIdx.x;
  int tx = threadIdx.x & 63, ty = threadIdx.x >> 6;
  int bf = flag[0];
  float gm = bf ? bf1(((const u16*)gamma)[ofs+tx]) : ((const float*)gamma)[ofs+tx];
  float be = bf ? bf1(((const u16*)beta)[ofs+tx])  : ((const float*)beta)[ofs+tx];
  float mean = s1[tx] * (1.f/NN);
  float var  = s2[tx] * (1.f/NN) - mean*mean;
  float rr = rsqrtf(fmaxf(var, 0.f) + 1e-5f);
  float sc = gm * rr;
  float sh = be - mean*sc;
  int st = starts[g], en = starts[g+1];
  float ls1 = 0.f, ls2 = 0.f;
  if (write_h){
    for (int n = st + ty; n < en; n += 4){
      float z = t[(size_t)n*NH + tx] * sc + sh;
      h[(size_t)n*NH + tx] = f16b(z);
      ls1 += z; ls2 += z*z;
    }
  } else {
    for (int n = st + ty; n < en; n += 4){
      float z = t[(size_t)n*NH + tx] * sc + sh;
      ls1 += z; ls2 += z*z;
    }
  }
  sRed[ty*NH + tx] = ls1;
  sRed[(4+ty)*NH + tx] = ls2;
  __syncthreads();
  if (ty == 0){
    float a1 = sRed[tx] + sRed[NH+tx] + sRed[2*NH+tx] + sRed[3*NH+tx];
    float a2 = sRed[4*NH+tx] + sRed[5*NH+tx] + sRed[6*NH+tx] + sRed[7*NH+tx];
    int cnt = en - st;
    float inv = 1.f / (float)max(cnt, 1);
    float m = a1 * inv;
    float vv = a2 * inv - m*m;
    float s = sqrtf(fmaxf(vv, 0.f));
    size_t eidx = ((size_t)layer*NG + g)*NH + tx;
    size_t sidx = (size_t)4*NG*NH + eidx;
    if (bf){
      ((__hip_bfloat16*)dout)[eidx] = __float2bfloat16(m);
      ((__hip_bfloat16*)dout)[sidx] = __float2bfloat16(s);
    } else {
      ((float*)dout)[eidx] = m;
      ((float*)dout)[sidx] = s;
    }
  }
}

// ---- MLP: f16 staging + f16-packed weights + fdot2, row-paired (R10, unchanged)
__global__ __launch_bounds__(256) void k_mlp_f(float* __restrict__ U,
    const float* __restrict__ W1, const float* __restrict__ W2, int wofs,
    float* __restrict__ s1, float* __restrict__ s2){
  __shared__ u32 sW1h[32*64];   // 8 KB
  __shared__ u32 sW2h[32*64];   // 8 KB
  __shared__ u16 sUh[64*64];    // 8 KB
  __shared__ u16 sVh[64*64];    // 8 KB
  __shared__ float sRed[8*NH];  // 2 KB
  int tid = threadIdx.x;
  for (int i = tid; i < 512; i += 256){
    int k2 = i >> 4, c4 = i & 15;
    float4 a1 = *(const float4*)(W1 + wofs + (size_t)(2*k2)*NH + c4*4);
    float4 b1 = *(const float4*)(W1 + wofs + (size_t)(2*k2+1)*NH + c4*4);
    uint4 s;
    s.x = pk(a1.x, b1.x); s.y = pk(a1.y, b1.y); s.z = pk(a1.z, b1.z); s.w = pk(a1.w, b1.w);
    *(uint4*)&sW1h[k2*64 + c4*4] = s;
    float4 a2 = *(const float4*)(W2 + wofs + (size_t)(2*k2)*NH + c4*4);
    float4 b2 = *(const float4*)(W2 + wofs + (size_t)(2*k2+1)*NH + c4*4);
    uint4 s2v;
    s2v.x = pk(a2.x, b2.x); s2v.y = pk(a2.y, b2.y); s2v.z = pk(a2.z, b2.z); s2v.w = pk(a2.w, b2.w);
    *(uint4*)&sW2h[k2*64 + c4*4] = s2v;
  }
  int node0 = blockIdx.x*64;
  int nrows = min(64, NN - node0);
  for (int i = tid; i < 1024; i += 256){
    int r = i >> 4, c4 = i & 15;
    float4 q;
    if (r < nrows) q = *(const float4*)&U[(size_t)(node0+r)*NH + c4*4];
    else { q.x=0.f; q.y=0.f; q.z=0.f; q.w=0.f; }
    uint2 w; w.x = pk(q.x, q.y); w.y = pk(q.z, q.w);
    *(uint2*)&sUh[r*64 + c4*4] = w;
  }
  __syncthreads();
  int tx = tid & 63, ty = tid >> 6;
  // phase A: V = relu(U @ W1)
  for (int i = 0; i < 8; i++){
    int ra = ty*16 + i, rb = ra + 8;
    float acca = 0.f, accb = 0.f;
    #pragma unroll
    for (int k8 = 0; k8 < 8; k8++){
      uint4 ua = *(const uint4*)&sUh[ra*64 + k8*8];
      uint4 ub = *(const uint4*)&sUh[rb*64 + k8*8];
      h2 w0 = uph(sW1h[(k8*4+0)*64 + tx]);
      h2 w1 = uph(sW1h[(k8*4+1)*64 + tx]);
      h2 w2 = uph(sW1h[(k8*4+2)*64 + tx]);
      h2 w3 = uph(sW1h[(k8*4+3)*64 + tx]);
      acca = fdot2(uph(ua.x), w0, acca); accb = fdot2(uph(ub.x), w0, accb);
      acca = fdot2(uph(ua.y), w1, acca); accb = fdot2(uph(ub.y), w1, accb);
      acca = fdot2(uph(ua.z), w2, acca); accb = fdot2(uph(ub.z), w2, accb);
      acca = fdot2(uph(ua.w), w3, acca); accb = fdot2(uph(ub.w), w3, accb);
    }
    sVh[ra*64 + tx] = f16b(fmaxf(acca, 0.f));
    sVh[rb*64 + tx] = f16b(fmaxf(accb, 0.f));
  }
  __syncthreads();
  // phase B: T = relu(V @ W2), in-place to U
  float ls1 = 0.f, ls2 = 0.f;
  for (int i = 0; i < 8; i++){
    int ra = ty*16 + i, rb = ra + 8;
    float acca = 0.f, accb = 0.f;
    #pragma unroll
    for (int k8 = 0; k8 < 8; k8++){
      uint4 va = *(const uint4*)&sVh[ra*64 + k8*8];
      uint4 vb = *(const uint4*)&sVh[rb*64 + k8*8];
      h2 w0 = uph(sW2h[(k8*4+0)*64 + tx]);
      h2 w1 = uph(sW2h[(k8*4+1)*64 + tx]);
      h2 w2 = uph(sW2h[(k8*4+2)*64 + tx]);
      h2 w3 = uph(sW2h[(k8*4+3)*64 + tx]);
      acca = fdot2(uph(va.x), w0, acca); accb = fdot2(uph(vb.x), w0, accb);
      acca = fdot2(uph(va.y), w1, acca); accb = fdot2(uph(vb.y), w1, accb);
      acca = fdot2(uph(va.z), w2, acca); accb = fdot2(uph(vb.z), w2, accb);
      acca = fdot2(uph(va.w), w3, acca); accb = fdot2(uph(vb.w), w3, accb);
    }
    float ta = fmaxf(acca, 0.f), tb = fmaxf(accb, 0.f);
    if (ra < nrows){ U[(size_t)(node0+ra)*NH + tx] = ta; ls1 += ta; ls2 += ta*ta; }
    if (rb < nrows){ U[(size_t)(node0+rb)*NH + tx] = tb; ls1 += tb; ls2 += tb*tb; }
  }
  __syncthreads();
  sRed[ty*NH + tx] = ls1;
  sRed[(4+ty)*NH + tx] = ls2;
  __syncthreads();
  if (ty == 0){
    float a1 = sRed[tx] + sRed[NH+tx] + sRed[2*NH+tx] + sRed[3*NH+tx];
    float a2 = sRed[4*NH+tx] + sRed[5*NH+tx] + sRed[6*NH+tx] + sRed[7*NH+tx];
    unsafeAtomicAdd(&s1[tx], a1);
    unsafeAtomicAdd(&s2[tx], a2);
  }
}

extern "C" void kernel_launch(void* const* d_in, const int* in_sizes, int n_in,
                              void* d_out, int out_size, void* d_ws, size_t ws_size,
                              hipStream_t stream) {
  const void* x    = d_in[0];
  const int* ei    = (const int*)d_in[1];
  const int* batch = (const int*)d_in[2];
  const void* Wt   = d_in[3];
  const void* bt   = d_in[4];
  const void* g0   = d_in[5];
  const void* b0   = d_in[6];
  const void* W1   = d_in[7];
  const void* W2   = d_in[8];
  const void* gs   = d_in[9];
  const void* bs   = d_in[10];

  u16*  hbuf = (u16*)d_ws;                      // NN*NH f16 (in NN*NH*4-byte slot)
  float* ubuf = (float*)d_ws + (size_t)NN*NH;   // NN*NH f32 (U, then in-place T)
  float* s1   = ubuf + (size_t)NN*NH;           // 64
  float* s2   = s1 + NH;                        // 64 (contiguous after s1)
  float* pad  = s2 + NH;                        // 128 (layout spacer)
  int* starts = (int*)(pad + 2*NH);             // 512
  int* flag   = starts + 512;                   // 64 (padded)
  int* deg    = flag + 64;                      // NN
  int* rowptr = deg + NN;                       // NN+64
  int* cursor = rowptr + NN + 64;               // NN
  int* csr    = cursor + NN;                    // NE
  int* bsum   = csr + NE;                       // 256

  hipMemsetAsync(s1, 0, 2*NH*sizeof(float), stream);
  hipMemsetAsync(deg, 0, NN*sizeof(int), stream);
  k_detect<<<1, 64, 0, stream>>>((const u32*)x, flag);
  k_bounds<<<1, 512, 0, stream>>>(batch, starts);
  k_count<<<(NE+255)/256, 256, 0, stream>>>(ei, deg);
  k_scanA<<<SCAN_B, 256, 0, stream>>>(deg, bsum);
  k_scanB<<<1, 256, 0, stream>>>(bsum);
  k_scanC<<<SCAN_B, 256, 0, stream>>>(deg, bsum, rowptr, cursor);
  k_fill<<<(NE+255)/256, 256, 0, stream>>>(ei, cursor, csr);

  k_transform_f<<<(NN+31)/32, 256, 0, stream>>>((const float*)x, (const float*)Wt, (const float*)bt, ubuf, s1, s2);
  k_embed<<<NG, 256, 0, stream>>>(ubuf, s1, s2, g0, b0, 0, hbuf, 1, starts, flag, d_out, 0);

  for (int l = 0; l < 3; l++){
    k_gather<<<(NN+3)/4, 256, 0, stream>>>(hbuf, rowptr, csr, ubuf, s1);  // also zeros s1/s2
    k_mlp_f<<<(NN+63)/64, 256, 0, stream>>>(ubuf, (const float*)W1, (const float*)W2, l*NH*NH, s1, s2);
    k_embed<<<NG, 256, 0, stream>>>(ubuf, s1, s2, gs, bs, l*NH, hbuf, (l < 2) ? 1 : 0, starts, flag, d_out, l+1);
  }
}